// Round 10
// baseline (507.599 us; speedup 1.0000x reference)
//
#include <hip/hip_runtime.h>
#include <stdint.h>

typedef unsigned int u32;
typedef unsigned long long u64;
typedef _Float16 f16;
typedef __attribute__((ext_vector_type(8))) _Float16 f16x8;
typedef __attribute__((ext_vector_type(4))) float f32x4;

#define NB 4
#define CIN 256
#define HW 80
#define PX (HW*HW)            // 6400
#define NA 9
#define NANCH (PX*NA)         // 57600
#define PRE 1000
#define POST 300
#define CANDN 4096

// d_out layout (floats): fg[4*57600], rpn_reg[4*57600*4], rois[4*300*4]
#define O_REG  (NB*NANCH)             // 230400
#define O_ROIS (O_REG + NB*NANCH*4)   // 1152000

// workspace byte offsets (all 16B aligned)
#define WS_WPREP 0ull          // 72 taps * 32KB = 2359296 B (slack to 2949120)
#define WS_BASE  2949120ull    // 4*6400*256 f ([n][p][ci]) = 26214400 B
#define WS_BOX   29163520ull   // 4*57600*4 f  = 3686400 B
#define WS_KEY   32849920ull   // 4*57600 u32  = 921600 B
#define WS_GH    33771520ull   // 4*64*2048 u32 (u16-packed 4096 bins) = 2097152 B
#define WS_TBOX  35868672ull   // 4*1000*4 f   = 64000 B
#define WS_MASK  35932672ull   // 4*1000*16 u64= 512000 B

// anchor widths/heights (base=32, scales 8/16/32, ratios .5/1/2 with np rounding)
__constant__ float c_aw[9] = {360.f,720.f,1440.f,256.f,512.f,1024.f,184.f,368.f,736.f};
__constant__ float c_ah[9] = {176.f,352.f,704.f,256.f,512.f,1024.f,368.f,736.f,1472.f};

// ---- weight prep: fp32 w[co][ci][t] -> glds-ready tap blocks (32KB each).
// Within cb-half: row co (0..127) at co*128B; chunk (m,q) 16B at
// ((m*64+q*16) ^ ((co&7)<<4)) holding f16 of (m? residual*4096 : value),
// ci = cb8*32 + q*8 .. +8.
__global__ void k_prepw(const float* __restrict__ w, f16* __restrict__ Wp)
{
    int id = blockIdx.x*256 + threadIdx.x;
    if (id >= 72*256) return;
    int co = id & 255;
    int tc = id >> 8;            // t*8+cb8
    int t = tc >> 3, cb8 = tc & 7;
    __align__(16) f16 hb[32];
    __align__(16) f16 mb[32];
    #pragma unroll
    for (int ci = 0; ci < 32; ++ci) {
        float wv = w[((size_t)co*256 + (cb8*32 + ci))*9 + t];
        f16 h = (f16)wv;
        f16 m = (f16)((wv - (float)h) * 4096.f);
        hb[ci] = h; mb[ci] = m;
    }
    char* row = (char*)Wp + (size_t)tc*32768
              + (size_t)(co >> 7)*16384        // cb half
              + (size_t)(co & 127)*128;        // row within half
    int sw = (co & 7) << 4;
    #pragma unroll
    for (int mq = 0; mq < 8; ++mq) {
        int m_ = mq >> 2, qc = mq & 3;
        int off = ((m_*64 + qc*16) ^ sw);
        *(f16x8*)(row + off) = *(const f16x8*)((m_ ? mb : hb) + qc*8);
    }
}

// ---- conv3x3 (implicit GEMM, fp16-split MFMA, register-pipelined) -> base [n][p][ci]
// 400 blocks: 2 co-halves x 200 px-tiles (8h x 16w). 4 waves = 2co x 2px,
// wave tile 64co x 64px. Per tap: issue glds W(t+2) -> hh MFMAs ->
// s_waitcnt vmcnt(4) lgkmcnt(0) -> RAW s_barrier (no compiler drain; makes
// every wave's W(t+1) pieces visible block-wide, since staging is
// block-cooperative and vmcnt is per-wave — the r7/r8 race) -> prefetch
// next-tap Ah/Bh regs -> hm+mh MFMAs. W(t+2) stays in flight across the
// barrier (counted vmcnt). X re-staged behind full __syncthreads per 9 taps.
__launch_bounds__(256, 2)
__global__ void k_conv3(const float* __restrict__ x, const f16* __restrict__ Wp,
                        const float* __restrict__ cbias,
                        const float* __restrict__ g1, const float* __restrict__ b1,
                        const float* __restrict__ m1, const float* __restrict__ v1,
                        float* __restrict__ base)
{
    __shared__ __align__(16) char ldsW[3][16384];   // [buf][128 co][128B swz]
    __shared__ __align__(16) char ldsX[23040];      // [180 pos][128B h|m swz]
    int tid = threadIdx.x;
    int lane = tid & 63, wid = tid >> 6;
    int q = lane >> 4, l16 = lane & 15;
    int wc = (wid >> 1) * 64, wr = (wid & 1) * 4;
    int virt = (blockIdx.x & 7)*50 + (blockIdx.x >> 3);  // XCD-chunked (400%8==0)
    int cb = virt & 1, pxb = virt >> 1;
    int n = pxb / 50, rem = pxb % 50;
    int h0 = (rem/5)*8, w0 = (rem%5)*16;
    const float* xn = x + (size_t)n*CIN*PX;

    // A-frag byte offsets (row = wc + i*16 + l16; row&7 == l16&7)
    int aswz = (l16 & 7) << 4;
    int aoffH[4], aoffM[4];
    #pragma unroll
    for (int i = 0; i < 4; ++i) {
        aoffH[i] = (wc + i*16 + l16)*128 + ((q*16)      ^ aswz);
        aoffM[i] = (wc + i*16 + l16)*128 + ((q*16 + 64) ^ aswz);
    }

    f32x4 acch[4][4], accl[4][4];
    #pragma unroll
    for (int i = 0; i < 4; ++i)
        #pragma unroll
        for (int j = 0; j < 4; ++j) {
            acch[i][j] = (f32x4){0.f,0.f,0.f,0.f};
            accl[i][j] = (f32x4){0.f,0.f,0.f,0.f};
        }

    // X halo stage: quarter-wave per (r, ci) row; coalesced 128B row segments.
    auto stageX = [&](int cb8) {
        int ci0 = cb8 * 32;
        int s = tid & 15;
        int wv = w0 - 8 + 2*s;
        #pragma unroll 2
        for (int it = 0; it < 20; ++it) {
            int task = it*16 + (tid >> 4);        // 0..319
            int r = task >> 5, ci = task & 31;
            int hh = h0 - 1 + r;
            bool rok = (hh >= 0) && (hh < HW);
            const float* srow = xn + (size_t)(ci0 + ci)*PX + hh*HW;
            float v0 = (rok && wv >= 0 && wv < HW)       ? srow[wv]   : 0.f;
            float v1_ = (rok && wv+1 >= 0 && wv+1 < HW)  ? srow[wv+1] : 0.f;
            int qc16 = (ci >> 3) * 16, e2 = (ci & 7) * 2;
            int c0 = wv - w0 + 1;
            if (c0 >= 0 && c0 < 18) {
                int pos = r*18 + c0, sw = (pos & 7) << 4;
                f16 h = (f16)v0, m = (f16)((v0 - (float)h) * 4096.f);
                *(f16*)(ldsX + pos*128 + ((qc16)      ^ sw) + e2) = h;
                *(f16*)(ldsX + pos*128 + ((qc16 + 64) ^ sw) + e2) = m;
            }
            int c1 = c0 + 1;
            if (c1 >= 0 && c1 < 18) {
                int pos = r*18 + c1, sw = (pos & 7) << 4;
                f16 h = (f16)v1_, m = (f16)((v1_ - (float)h) * 4096.f);
                *(f16*)(ldsX + pos*128 + ((qc16)      ^ sw) + e2) = h;
                *(f16*)(ldsX + pos*128 + ((qc16 + 64) ^ sw) + e2) = m;
            }
        }
    };

    // block-wide async W stage: 16KB, 4 x 16B chunks per thread
    auto gldsW = [&](int tap, int bufi) {
        const char* src = (const char*)Wp + (size_t)tap*32768 + (size_t)cb*16384;
        char* dst = &ldsW[bufi][0];
        #pragma unroll
        for (int c = 0; c < 4; ++c) {
            int k = (c*256 + tid) * 16;
            __builtin_amdgcn_global_load_lds(
                (const __attribute__((address_space(1))) void*)(src + k),
                (__attribute__((address_space(3))) void*)(dst + k), 16, 0, 0);
        }
    };

    f16x8 Ah0[4], Bh0[4], Ah1[4], Bh1[4];   // double-buffered h frags
    f16x8 Am[4], Bm[4];                     // single-buffered m frags

#define READ_AH(DST, BUFI) { const char* W_ = &ldsW[BUFI][0]; \
    _Pragma("unroll") for (int i_ = 0; i_ < 4; ++i_) \
        DST[i_] = *(const f16x8*)(W_ + aoffH[i_]); }
#define READ_AM(BUFI) { const char* W_ = &ldsW[BUFI][0]; \
    _Pragma("unroll") for (int i_ = 0; i_ < 4; ++i_) \
        Am[i_] = *(const f16x8*)(W_ + aoffM[i_]); }
#define READ_BH(DST, T9) { int dh_ = (T9)/3, dw_ = (T9) - 3*dh_; \
    _Pragma("unroll") for (int j_ = 0; j_ < 4; ++j_) { \
        int pos = (wr + j_ + dh_)*18 + l16 + dw_; int sw_ = (pos & 7) << 4; \
        DST[j_] = *(const f16x8*)(ldsX + pos*128 + ((q*16) ^ sw_)); } }
#define READ_BM(T9) { int dh_ = (T9)/3, dw_ = (T9) - 3*dh_; \
    _Pragma("unroll") for (int j_ = 0; j_ < 4; ++j_) { \
        int pos = (wr + j_ + dh_)*18 + l16 + dw_; int sw_ = (pos & 7) << 4; \
        Bm[j_] = *(const f16x8*)(ldsX + pos*128 + ((q*16 + 64) ^ sw_)); } }

    // prologue: W(0)->buf0, W(1)->buf1, X(group 0); __syncthreads drains all
    gldsW(0, 0);
    gldsW(8, 1);          // taptc(1) = (1%9)*8 + 0 = 8
    stageX(0);
    __syncthreads();
    READ_AH(Ah0, 0);
    READ_BH(Bh0, 0);

// BC = tg%3 (current W buf), BN = (tg+1)%3 (next), BP = (tg+2)%3 (glds dest).
// Safety invariants: (a) any read of W buffer K happens only AFTER a block
// barrier that followed every wave's s_waitcnt retiring its own staging loads
// for K (mid-tap barrier of tap t-1 for BC-reads, of tap t for AhN-reads);
// (b) glds into BP issues only after the t-1 mid barrier whose lgkmcnt(0)
// retired all waves' last ds_reads of that buffer.
#define BODY(TG, AhC, BhC, AhN, BhN, BC, BN, BP) { \
    const int tg_ = (TG); int t9_ = tg_ % 9; \
    if (t9_ == 0 && tg_) { \
        __syncthreads(); \
        stageX(tg_ / 9); \
        __syncthreads(); \
        READ_BH(BhC, 0); \
    } \
    if (tg_ + 2 < 72) gldsW(((tg_+2) % 9)*8 + (tg_+2)/9, (BP)); \
    READ_AM(BC); \
    READ_BM(t9_); \
    _Pragma("unroll") for (int j_ = 0; j_ < 4; ++j_) \
        _Pragma("unroll") for (int i_ = 0; i_ < 4; ++i_) \
            acch[i_][j_] = __builtin_amdgcn_mfma_f32_16x16x32_f16(AhC[i_], BhC[j_], acch[i_][j_], 0, 0, 0); \
    if (tg_ < 71) { \
        /* vmcnt(4): W(t+1) retired (W(t+2) stays in flight); lgkmcnt(0): */ \
        /* this wave's ds_reads of BP-buffer retired before others' writes */ \
        if (tg_ < 70) { __builtin_amdgcn_s_waitcnt(0x0074); } \
        else          { __builtin_amdgcn_s_waitcnt(0x0070); } \
        __builtin_amdgcn_sched_barrier(0); \
        __builtin_amdgcn_s_barrier(); \
        __builtin_amdgcn_sched_barrier(0); \
        READ_AH(AhN, BN); \
        if (t9_ != 8) READ_BH(BhN, t9_ + 1); \
    } \
    _Pragma("unroll") for (int j_ = 0; j_ < 4; ++j_) \
        _Pragma("unroll") for (int i_ = 0; i_ < 4; ++i_) \
            accl[i_][j_] = __builtin_amdgcn_mfma_f32_16x16x32_f16(AhC[i_], Bm[j_], accl[i_][j_], 0, 0, 0); \
    _Pragma("unroll") for (int j_ = 0; j_ < 4; ++j_) \
        _Pragma("unroll") for (int i_ = 0; i_ < 4; ++i_) \
            accl[i_][j_] = __builtin_amdgcn_mfma_f32_16x16x32_f16(Am[i_], BhC[j_], accl[i_][j_], 0, 0, 0); \
}

    for (int tp = 0; tp < 12; ++tp) {       // 72 taps = 12 x 6 (lcm of 2-reg, 3-lds bufs)
        BODY(6*tp + 0, Ah0, Bh0, Ah1, Bh1, 0, 1, 2);
        BODY(6*tp + 1, Ah1, Bh1, Ah0, Bh0, 1, 2, 0);
        BODY(6*tp + 2, Ah0, Bh0, Ah1, Bh1, 2, 0, 1);
        BODY(6*tp + 3, Ah1, Bh1, Ah0, Bh0, 0, 1, 2);
        BODY(6*tp + 4, Ah0, Bh0, Ah1, Bh1, 1, 2, 0);
        BODY(6*tp + 5, Ah1, Bh1, Ah0, Bh0, 2, 0, 1);
    }
#undef BODY
#undef READ_AH
#undef READ_AM
#undef READ_BH
#undef READ_BM

    // epilogue: combine splits, bias + mish + bn1, store base[n][p][ci]
    #pragma unroll
    for (int i = 0; i < 4; ++i) {
        #pragma unroll
        for (int rg = 0; rg < 4; ++rg) {
            int co = cb*128 + wc + i*16 + q*4 + rg;
            float cbv = cbias[co];
            float inv = g1[co] / sqrtf(v1[co] + 1e-5f);
            float ad  = b1[co] - m1[co]*inv;
            #pragma unroll
            for (int j = 0; j < 4; ++j) {
                float tval = acch[i][j][rg] + accl[i][j][rg]*(1.f/4096.f) + cbv;
                float sp = fmaxf(tval, 0.f) + log1pf(expf(-fabsf(tval)));  // softplus
                float mi = tval * tanhf(sp);                               // mish
                int p = (h0 + wr + j)*HW + w0 + l16;
                base[((size_t)n*PX + p)*256 + co] = mi*inv + ad;
            }
        }
    }
}

// ---- 1x1 heads + bn2/softmax (fg) + bn3 (rpn_reg) -> d_out (base [n][p][ci]) ----
__launch_bounds__(128)
__global__ void k_heads(const float* __restrict__ base,
                        const float* __restrict__ clsw, const float* __restrict__ regw,
                        const float* __restrict__ g2, const float* __restrict__ b2,
                        const float* __restrict__ m2, const float* __restrict__ v2,
                        const float* __restrict__ g3, const float* __restrict__ b3,
                        const float* __restrict__ m3, const float* __restrict__ v3,
                        float* __restrict__ out)
{
    __shared__ float wt[256*56];   // [ci][co<54]  (co: 0..17 cls, 18..53 reg)
    int tid = threadIdx.x;
    for (int i = tid; i < 54*256; i += 128) {
        int co = i >> 8, ci = i & 255;
        float v = (co < 18) ? clsw[i] : regw[i - 18*256];
        wt[ci*56 + co] = v;
    }
    __syncthreads();
    int gp = blockIdx.x*128 + tid;           // 0..25599
    int n = gp / PX, p = gp % PX;
    float acc[54];
    #pragma unroll
    for (int i = 0; i < 54; ++i) acc[i] = 0.f;
    const float4* bpv = (const float4*)(base + ((size_t)n*PX + p)*256);
    for (int c = 0; c < 64; ++c) {
        float4 xq = bpv[c];
        #pragma unroll
        for (int e = 0; e < 4; ++e) {
            float xv = (e == 0) ? xq.x : (e == 1) ? xq.y : (e == 2) ? xq.z : xq.w;
            const float* wr = &wt[(c*4 + e)*56];
            #pragma unroll
            for (int co = 0; co < 54; ++co) acc[co] = fmaf(wr[co], xv, acc[co]);
        }
    }
    int fgb = n*NANCH + p*NA;
    #pragma unroll
    for (int a = 0; a < NA; ++a) {
        float i0 = g2[2*a]   / sqrtf(v2[2*a]   + 1e-5f);
        float i1 = g2[2*a+1] / sqrtf(v2[2*a+1] + 1e-5f);
        float s0 = acc[2*a]*i0   + (b2[2*a]   - m2[2*a]*i0);
        float s1 = acc[2*a+1]*i1 + (b2[2*a+1] - m2[2*a+1]*i1);
        float mx = fmaxf(s0, s1);
        float e0 = expf(s0 - mx), e1 = expf(s1 - mx);
        out[fgb + a] = e1 / (e0 + e1);
    }
    size_t rb = (size_t)O_REG + (size_t)n*NANCH*4 + (size_t)p*36;
    #pragma unroll
    for (int c = 0; c < 36; ++c) {
        float iv = g3[c] / sqrtf(v3[c] + 1e-5f);
        out[rb + c] = acc[18 + c]*iv + (b3[c] - m3[c]*iv);
    }
}

// ---- decode + clip + min-size filter + sortable key (pure streaming, no atomics) ----
__global__ void k_decode(const float* __restrict__ out,
                         float* __restrict__ boxes, u32* __restrict__ keys)
{
    int gi = blockIdx.x*256 + threadIdx.x;   // 0..230399
    int n = gi / NANCH, i = gi % NANCH;
    int a = i % NA, p = i / NA;
    int wx = p % HW, hy = p / HW;
    const float4 d = *(const float4*)&out[O_REG + (size_t)n*NANCH*4 + (size_t)i*4];
    float aw = c_aw[a], ah = c_ah[a];
    float acx = 16.f + 16.f*(float)wx;
    float acy = 16.f + 16.f*(float)hy;
    float pcx = d.x*aw + acx;
    float pcy = d.y*ah + acy;
    float pw = expf(d.z)*aw;
    float ph = expf(d.w)*ah;
    float x1 = fminf(fmaxf(pcx - 0.5f*pw, 0.f), 1279.f);
    float y1 = fminf(fmaxf(pcy - 0.5f*ph, 0.f), 1279.f);
    float x2 = fminf(fmaxf(pcx + 0.5f*pw, 0.f), 1279.f);
    float y2 = fminf(fmaxf(pcy + 0.5f*ph, 0.f), 1279.f);
    float wsz = x2 - x1 + 1.f, hsz = y2 - y1 + 1.f;
    float sc = out[(size_t)n*NANCH + i];
    float s = (wsz >= 16.f && hsz >= 16.f) ? sc : -1e9f;
    *(float4*)&boxes[((size_t)n*NANCH + i)*4] = make_float4(x1, y1, x2, y2);
    u32 u = __float_as_uint(s);
    u = (u & 0x80000000u) ? ~u : (u | 0x80000000u);   // monotone order-preserving map
    keys[(size_t)n*NANCH + i] = u;
}

// ---- per-slice 12-bit histograms (LDS-only atomics, exclusive global slices) ----
__launch_bounds__(256)
__global__ void k_hist(const u32* __restrict__ keys, u32* __restrict__ ghp)
{
    __shared__ u32 hh[4096];
    int bid = blockIdx.x;              // 256 = 4 n x 64 slices
    int n = bid >> 6, slice = bid & 63;
    int tid = threadIdx.x;
    #pragma unroll
    for (int k = 0; k < 16; ++k) hh[tid + k*256] = 0;
    __syncthreads();
    const u32* kp = keys + (size_t)n*NANCH + slice*900;
    for (int i = tid; i < 900; i += 256)
        atomicAdd(&hh[kp[i] >> 20], 1u);
    __syncthreads();
    u32* gp = ghp + ((size_t)n*64 + slice)*2048;
    #pragma unroll
    for (int k = 0; k < 8; ++k) {
        int j = tid + k*256;
        gp[j] = (hh[2*j] & 0xFFFFu) | (hh[2*j+1] << 16);
    }
}

// ---- two-level (12+12 bit) radix-select + compact + bitonic -> top-1000 boxes ----
__launch_bounds__(1024)
__global__ void k_select(const u32* __restrict__ keys, const u32* __restrict__ ghp,
                         const float* __restrict__ boxes, float* __restrict__ topbox)
{
    __shared__ u32 h1[4096];
    __shared__ u32 h2[4][4096];
    __shared__ u32 ss[1025];
    __shared__ int sB1, sA1, sB2, scnt;
    __shared__ u64 cand[CANDN];
    int n = blockIdx.x, tid = threadIdx.x, wid = tid >> 6;

    // pass 0: reduce 64 u16 slices -> h1
    const u32* gp = ghp + (size_t)n*64*2048;
    u32 c0=0,c1=0,c2=0,c3=0;
    for (int s = 0; s < 64; ++s) {
        const u32* w = gp + s*2048 + 2*tid;
        u32 a = w[0], b = w[1];
        c0 += a & 0xFFFFu; c1 += a >> 16; c2 += b & 0xFFFFu; c3 += b >> 16;
    }
    h1[4*tid+0]=c0; h1[4*tid+1]=c1; h1[4*tid+2]=c2; h1[4*tid+3]=c3;
    ss[tid] = c0+c1+c2+c3;
    if (tid == 0) scnt = 0;
    __syncthreads();
    for (int off = 1; off < 1024; off <<= 1) {   // suffix sums
        u32 v = (tid + off < 1024) ? ss[tid + off] : 0u;
        __syncthreads();
        ss[tid] += v;
        __syncthreads();
    }
    {
        u32 nxt = (tid == 1023) ? 0u : ss[tid + 1];
        if (ss[tid] >= PRE && nxt < PRE) {
            u32 c = nxt;
            for (int b = 4*tid+3; b >= 4*tid; --b) {
                c += h1[b];
                if (c >= PRE) { sB1 = b; sA1 = (int)(c - h1[b]); break; }
            }
        }
    }
    __syncthreads();
    int B1 = sB1, A1 = sA1;
    for (int k = tid; k < 4*4096; k += 1024) ((u32*)h2)[k] = 0;
    __syncthreads();

    // pass 1: emit strict-above candidates; histogram boundary bin's next 12 bits
    const u32* kp = keys + (size_t)n*NANCH;
    for (int i = tid; i < NANCH; i += 1024) {
        u32 k = kp[i];
        int top = (int)(k >> 20);
        if (top > B1) {
            int pos = atomicAdd(&scnt, 1);
            if (pos < CANDN) cand[pos] = ~(((u64)k << 32) | (u64)(0xFFFFFFFFu - (u32)i));
        } else if (top == B1) {
            atomicAdd(&h2[wid & 3][(k >> 8) & 0xFFFu], 1u);
        }
    }
    __syncthreads();
    {
        int b = 4*tid;
        u32 d0 = h2[0][b]+h2[1][b]+h2[2][b]+h2[3][b];
        u32 d1 = h2[0][b+1]+h2[1][b+1]+h2[2][b+1]+h2[3][b+1];
        u32 d2 = h2[0][b+2]+h2[1][b+2]+h2[2][b+2]+h2[3][b+2];
        u32 d3 = h2[0][b+3]+h2[1][b+3]+h2[2][b+3]+h2[3][b+3];
        ss[tid] = d0+d1+d2+d3;
    }
    __syncthreads();
    for (int off = 1; off < 1024; off <<= 1) {
        u32 v = (tid + off < 1024) ? ss[tid + off] : 0u;
        __syncthreads();
        ss[tid] += v;
        __syncthreads();
    }
    {
        u32 nxt = (tid == 1023) ? 0u : ss[tid + 1];
        if ((u32)A1 + ss[tid] >= PRE && (u32)A1 + nxt < PRE) {
            u32 c = (u32)A1 + nxt;
            for (int b = 4*tid+3; b >= 4*tid; --b) {
                u32 hv = h2[0][b]+h2[1][b]+h2[2][b]+h2[3][b];
                c += hv;
                if (c >= PRE) { sB2 = b; break; }
            }
        }
    }
    __syncthreads();
    int B2 = sB2;

    // pass 2: emit boundary-bin candidates with sub-key >= B2
    for (int i = tid; i < NANCH; i += 1024) {
        u32 k = kp[i];
        if ((int)(k >> 20) == B1 && (int)((k >> 8) & 0xFFFu) >= B2) {
            int pos = atomicAdd(&scnt, 1);
            if (pos < CANDN) cand[pos] = ~(((u64)k << 32) | (u64)(0xFFFFFFFFu - (u32)i));
        }
    }
    __syncthreads();
    int cnt = min(scnt, CANDN);
    for (int i = cnt + tid; i < CANDN; i += 1024) cand[i] = ~0ull;
    __syncthreads();
    for (int k = 2; k <= CANDN; k <<= 1) {       // bitonic ascending = (score desc, idx asc)
        for (int j = k >> 1; j > 0; j >>= 1) {
            for (int t = tid; t < CANDN/2; t += 1024) {
                int i1 = 2*t - (t & (j - 1));
                int i2 = i1 + j;
                u64 va = cand[i1], vb = cand[i2];
                bool up = ((i1 & k) == 0);
                if ((va > vb) == up) { cand[i1] = vb; cand[i2] = va; }
            }
            __syncthreads();
        }
    }
    for (int r = tid; r < PRE; r += 1024) {
        u64 c = ~cand[r];
        u32 idx = 0xFFFFFFFFu - (u32)(c & 0xFFFFFFFFull);
        *(float4*)&topbox[((size_t)n*PRE + r)*4] =
            *(const float4*)&boxes[((size_t)n*NANCH + idx)*4];
    }
}

// ---- IoU suppression bit-masks (64 blocks: 4 n x 16 chunks of 64 i) ----
__launch_bounds__(256)
__global__ void k_iou(const float* __restrict__ topbox, u64* __restrict__ masks)
{
    int n = blockIdx.x >> 4, chunk = blockIdx.x & 15;
    __shared__ float4 bs[PRE];
    for (int i = threadIdx.x; i < PRE; i += 256)
        bs[i] = *(const float4*)&topbox[((size_t)n*PRE + i)*4];
    __syncthreads();
    int il = threadIdx.x >> 2;          // 0..63
    int wq = threadIdx.x & 3;           // w-quarter: 4 words each
    int i = chunk*64 + il;
    if (i >= PRE) return;
    float4 bi = bs[i];
    float ai = (bi.z - bi.x + 1.f) * (bi.w - bi.y + 1.f);
    u64* mrow = masks + ((size_t)n*PRE + i)*16;
    for (int w = wq*4; w < wq*4 + 4; ++w) {
        u64 m = 0;
        int jn = min(64, PRE - w*64);
        for (int jj = 0; jj < jn; ++jj) {
            int j = w*64 + jj;
            float4 bj = bs[j];
            float xx1 = fmaxf(bi.x, bj.x);
            float yy1 = fmaxf(bi.y, bj.y);
            float xx2 = fminf(bi.z, bj.z);
            float yy2 = fminf(bi.w, bj.w);
            float iw = fmaxf(xx2 - xx1 + 1.f, 0.f);
            float ih = fmaxf(yy2 - yy1 + 1.f, 0.f);
            float inter = iw * ih;
            float aj = (bj.z - bj.x + 1.f) * (bj.w - bj.y + 1.f);
            float iou = inter / (ai + aj - inter);
            if ((j > i) && (iou > 0.7f)) m |= (1ull << jj);
        }
        mrow[w] = m;
    }
}

// ---- sequential NMS sweep (1 wave/batch, remv distributed over 16 lanes) + rois ----
__launch_bounds__(64)
__global__ void k_nms(const u64* __restrict__ masks, const float* __restrict__ topbox,
                      float* __restrict__ out)
{
    int n = blockIdx.x;
    int lane = threadIdx.x;
    int w = lane & 15;
    const u64* M = masks + (size_t)n*PRE*16;
    u64 remv = 0, keep = 0;
    u64 m0 = M[0*16+w], m1 = M[1*16+w], m2 = M[2*16+w], m3 = M[3*16+w];
    u64 m4 = M[4*16+w], m5 = M[5*16+w], m6 = M[6*16+w], m7 = M[7*16+w];
#define PROC(MR, II) { \
    int ii = (II); \
    u64 rw = __shfl(remv, ii >> 6, 64); \
    if (((rw >> (ii & 63)) & 1ull) == 0ull) { \
        remv |= MR; \
        if (w == (ii >> 6)) keep |= (1ull << (ii & 63)); \
    } }
    for (int b = 0; b < PRE; b += 8) {
        PROC(m0, b+0); m0 = (b+8  < PRE) ? M[(size_t)(b+8)*16 + w]  : 0ull;
        PROC(m1, b+1); m1 = (b+9  < PRE) ? M[(size_t)(b+9)*16 + w]  : 0ull;
        PROC(m2, b+2); m2 = (b+10 < PRE) ? M[(size_t)(b+10)*16 + w] : 0ull;
        PROC(m3, b+3); m3 = (b+11 < PRE) ? M[(size_t)(b+11)*16 + w] : 0ull;
        PROC(m4, b+4); m4 = (b+12 < PRE) ? M[(size_t)(b+12)*16 + w] : 0ull;
        PROC(m5, b+5); m5 = (b+13 < PRE) ? M[(size_t)(b+13)*16 + w] : 0ull;
        PROC(m6, b+6); m6 = (b+14 < PRE) ? M[(size_t)(b+14)*16 + w] : 0ull;
        PROC(m7, b+7); m7 = (b+15 < PRE) ? M[(size_t)(b+15)*16 + w] : 0ull;
    }
#undef PROC
    __shared__ int cnts[16];
    __shared__ int pfx[17];
    __shared__ u32 list[PRE];
    if (lane < 16) cnts[lane] = __popcll(keep);
    __syncthreads();
    if (lane == 0) {
        int s = 0;
        for (int t = 0; t < 16; ++t) { pfx[t] = s; s += cnts[t]; }
        pfx[16] = s;
    }
    __syncthreads();
    if (lane < 16) {
        int pos = pfx[lane];
        u64 kk = keep;
        for (int b = 0; b < 64; ++b)
            if ((kk >> b) & 1ull) list[pos++] = (u32)(lane*64 + b);
    }
    __syncthreads();
    int total = pfx[16];
    for (int k = lane; k < POST; k += 64) {
        float4 v = make_float4(0.f, 0.f, 0.f, 0.f);
        if (k < total) {
            u32 r = list[k];
            v = *(const float4*)&topbox[((size_t)n*PRE + r)*4];
        }
        *(float4*)&out[O_ROIS + ((size_t)n*POST + k)*4] = v;
    }
}

extern "C" void kernel_launch(void* const* d_in, const int* in_sizes, int n_in,
                              void* d_out, int out_size, void* d_ws, size_t ws_size,
                              hipStream_t stream)
{
    const float* x      = (const float*)d_in[0];
    const float* conv_w = (const float*)d_in[1];
    const float* conv_b = (const float*)d_in[2];
    const float* g1 = (const float*)d_in[3];
    const float* b1 = (const float*)d_in[4];
    const float* m1 = (const float*)d_in[5];
    const float* v1 = (const float*)d_in[6];
    const float* clsw = (const float*)d_in[7];
    const float* g2 = (const float*)d_in[8];
    const float* b2 = (const float*)d_in[9];
    const float* m2 = (const float*)d_in[10];
    const float* v2 = (const float*)d_in[11];
    const float* regw = (const float*)d_in[12];
    const float* g3 = (const float*)d_in[13];
    const float* b3 = (const float*)d_in[14];
    const float* m3 = (const float*)d_in[15];
    const float* v3 = (const float*)d_in[16];
    // d_in[17]/d_in[18] = img_h/img_w, fixed 1280 -> clip bound 1279.f hardcoded

    char* ws = (char*)d_ws;
    f16*   Wp     = (f16*)(ws + WS_WPREP);
    float* base   = (float*)(ws + WS_BASE);
    float* boxes  = (float*)(ws + WS_BOX);
    u32*   keys   = (u32*)(ws + WS_KEY);
    u32*   ghp    = (u32*)(ws + WS_GH);
    float* topbox = (float*)(ws + WS_TBOX);
    u64*   masks  = (u64*)(ws + WS_MASK);
    float* out = (float*)d_out;

    k_prepw<<<72, 256, 0, stream>>>(conv_w, Wp);
    k_conv3<<<400, 256, 0, stream>>>(x, Wp, conv_b, g1, b1, m1, v1, base);
    k_heads<<<200, 128, 0, stream>>>(base, clsw, regw, g2, b2, m2, v2, g3, b3, m3, v3, out);
    k_decode<<<900, 256, 0, stream>>>(out, boxes, keys);
    k_hist<<<256, 256, 0, stream>>>(keys, ghp);
    k_select<<<4, 1024, 0, stream>>>(keys, ghp, boxes, topbox);
    k_iou<<<64, 256, 0, stream>>>(topbox, masks);
    k_nms<<<4, 64, 0, stream>>>(masks, topbox, out);
}

// Round 11
// 466.301 us; speedup vs baseline: 1.0886x; 1.0886x over previous
//
#include <hip/hip_runtime.h>
#include <stdint.h>

typedef unsigned int u32;
typedef unsigned long long u64;
typedef _Float16 f16;
typedef __attribute__((ext_vector_type(8))) _Float16 f16x8;
typedef __attribute__((ext_vector_type(4))) float f32x4;

#define NB 4
#define CIN 256
#define HW 80
#define PX (HW*HW)            // 6400
#define NA 9
#define NANCH (PX*NA)         // 57600
#define PRE 1000
#define POST 300
#define CANDN 4096

// d_out layout (floats): fg[4*57600], rpn_reg[4*57600*4], rois[4*300*4]
#define O_REG  (NB*NANCH)             // 230400
#define O_ROIS (O_REG + NB*NANCH*4)   // 1152000

// workspace byte offsets (all 16B aligned)
#define WS_WPREP 0ull          // 9*8*2*256*40 f16 = 2949120 B
#define WS_BASE  2949120ull    // 4*256*6400 f ([n][co][p]) = 26214400 B
#define WS_BOX   29163520ull   // 4*57600*4 f  = 3686400 B
#define WS_KEY   32849920ull   // 4*57600 u32  = 921600 B
#define WS_GH    33771520ull   // 4*64*2048 u32 (u16-packed 4096 bins) = 2097152 B
#define WS_TBOX  35868672ull   // 4*1000*4 f   = 64000 B
#define WS_MASK  35932672ull   // 4*1000*16 u64= 512000 B

// anchor widths/heights (base=32, scales 8/16/32, ratios .5/1/2 with np rounding)
__constant__ float c_aw[9] = {360.f,720.f,1440.f,256.f,512.f,1024.f,184.f,368.f,736.f};
__constant__ float c_ah[9] = {176.f,352.f,704.f,256.f,512.f,1024.f,368.f,736.f,1472.f};

// ---- weight prep: fp32 w[co][ci][t] -> fp16 (h, m=residual*4096) in staging layout
// Wp[(t*8+cib)*20480 + part*10240 + co*40 + ci_local], rows padded 32->40 (80B)
__global__ void k_prepw(const float* __restrict__ w, f16* __restrict__ Wp)
{
    int id = blockIdx.x*256 + threadIdx.x;
    if (id >= 9*8*256) return;
    int co = id & 255;
    int tc = id >> 8;            // t*8+cib
    int t = tc >> 3, cib = tc & 7;
    __align__(16) f16 hb[40];
    __align__(16) f16 mb[40];
    #pragma unroll
    for (int k = 32; k < 40; ++k) { hb[k] = (f16)0.f; mb[k] = (f16)0.f; }
    #pragma unroll
    for (int ci = 0; ci < 32; ++ci) {
        float wv = w[((size_t)co*256 + (cib*32 + ci))*9 + t];
        f16 h = (f16)wv;
        f16 m = (f16)((wv - (float)h) * 4096.f);
        hb[ci] = h; mb[ci] = m;
    }
    f16* oh = Wp + (size_t)tc*20480 + (size_t)co*40;
    f16* om = oh + 10240;
    #pragma unroll
    for (int k = 0; k < 5; ++k) {
        *(f16x8*)(oh + k*8) = *(const f16x8*)(hb + k*8);
        *(f16x8*)(om + k*8) = *(const f16x8*)(mb + k*8);
    }
}

// ---- conv3x3 (implicit GEMM, fp16-split MFMA) + bias + mish + bn1 -> base (NCHW fp32)
// r2-exact (best measured: 196 us). block: 256 thr = 4 waves (2co x 2px),
// tile 128co x 128px (16w x 8h), K-step 32ci x 9 taps, 2 barriers per tap.
__launch_bounds__(256, 2)
__global__ void k_conv3(const float* __restrict__ x, const f16* __restrict__ Wp,
                        const float* __restrict__ cbias,
                        const float* __restrict__ g1, const float* __restrict__ b1,
                        const float* __restrict__ m1, const float* __restrict__ v1,
                        float* __restrict__ base)
{
    __shared__ __align__(16) f16 ldsA[10240];  // [2 part][128 co][40 (32ci+pad)]
    __shared__ __align__(16) f16 ldsX[14400];  // [2 part][180 pos][40 (32ci+pad)]
    int tid = threadIdx.x;
    int lane = tid & 63, wid = tid >> 6;
    int q = lane >> 4, l16 = lane & 15;
    int wc = (wid >> 1) * 64, wr = (wid & 1) * 4;
    int bid = blockIdx.x;
    int cb = bid & 1, pxb = bid >> 1;
    int n = pxb / 50, rem = pxb % 50;
    int h0 = (rem / 5) * 8, w0 = (rem % 5) * 16;

    f32x4 acch[4][4], accl[4][4];
    #pragma unroll
    for (int i = 0; i < 4; ++i)
        #pragma unroll
        for (int j = 0; j < 4; ++j) {
            acch[i][j] = (f32x4){0.f,0.f,0.f,0.f};
            accl[i][j] = (f32x4){0.f,0.f,0.f,0.f};
        }

    const float* xn = x + (size_t)n*CIN*PX;

    for (int cb8 = 0; cb8 < 8; ++cb8) {
        int ci0 = cb8 * 32;
        for (int t = 0; t < 9; ++t) {
            __syncthreads();                    // all waves done reading prev tiles
            if (t == 0) {
                // stage X halo: 10 rows x 18 cols x 32 ci, fp32 -> (h, m*4096) fp16
                for (int task = tid; task < 320; task += 256) {
                    int r = task >> 5, ci = task & 31;
                    int hh = h0 - 1 + r;
                    bool rowok = (hh >= 0) && (hh < HW);
                    const float* src = xn + (size_t)(ci0 + ci)*PX + hh*HW + (w0 - 1);
                    f16* dh = ldsX + r*18*40 + ci;
                    f16* dm = dh + 7200;
                    #pragma unroll
                    for (int cc = 0; cc < 18; ++cc) {
                        int ww = w0 - 1 + cc;
                        float v = (rowok && ww >= 0 && ww < HW) ? src[cc] : 0.f;
                        f16 h = (f16)v;
                        f16 m = (f16)((v - (float)h) * 4096.f);
                        dh[cc*40] = h;
                        dm[cc*40] = m;
                    }
                }
            }
            // stage A: 10240 f16 = 1280 x 16B chunks, 5 per thread, coalesced
            {
                const f16* wsrc = Wp + (size_t)(t*8 + cb8)*20480;
                #pragma unroll
                for (int c = 0; c < 5; ++c) {
                    int idx = c*256 + tid;             // 0..1279
                    int part = idx / 640, off = idx - part*640;
                    *(f16x8*)(ldsA + (size_t)idx*8) =
                        *(const f16x8*)(wsrc + part*10240 + cb*5120 + off*8);
                }
            }
            __syncthreads();                    // staging visible

            int dh_ = t / 3, dw_ = t - dh_*3;
            f16x8 Ah[4], Am[4];
            #pragma unroll
            for (int i = 0; i < 4; ++i) {
                int e = (wc + i*16 + l16)*40 + q*8;
                Ah[i] = *(const f16x8*)(ldsA + e);
                Am[i] = *(const f16x8*)(ldsA + 5120 + e);
            }
            #pragma unroll
            for (int j = 0; j < 4; ++j) {
                int pos = (wr + j + dh_)*18 + l16 + dw_;
                int e = pos*40 + q*8;
                f16x8 Bh = *(const f16x8*)(ldsX + e);
                f16x8 Bm = *(const f16x8*)(ldsX + 7200 + e);
                #pragma unroll
                for (int i = 0; i < 4; ++i) {
                    acch[i][j] = __builtin_amdgcn_mfma_f32_16x16x32_f16(Ah[i], Bh, acch[i][j], 0, 0, 0);
                    accl[i][j] = __builtin_amdgcn_mfma_f32_16x16x32_f16(Ah[i], Bm, accl[i][j], 0, 0, 0);
                    accl[i][j] = __builtin_amdgcn_mfma_f32_16x16x32_f16(Am[i], Bh, accl[i][j], 0, 0, 0);
                }
            }
        }
    }
    // epilogue: combine splits, bias + mish + bn1, store NCHW fp32 ([n][co][p])
    #pragma unroll
    for (int i = 0; i < 4; ++i) {
        #pragma unroll
        for (int rg = 0; rg < 4; ++rg) {
            int co = cb*128 + wc + i*16 + q*4 + rg;
            float cbv = cbias[co];
            float inv = g1[co] / sqrtf(v1[co] + 1e-5f);
            float ad  = b1[co] - m1[co]*inv;
            #pragma unroll
            for (int j = 0; j < 4; ++j) {
                float tval = acch[i][j][rg] + accl[i][j][rg]*(1.f/4096.f) + cbv;
                float sp = fmaxf(tval, 0.f) + log1pf(expf(-fabsf(tval)));  // softplus
                float mi = tval * tanhf(sp);                               // mish
                int h = h0 + wr + j, w = w0 + l16;
                base[(size_t)(n*CIN + co)*PX + h*HW + w] = mi*inv + ad;
            }
        }
    }
}

// ---- 1x1 heads + bn2/softmax (fg) + bn3 (rpn_reg) -> d_out (base [n][co][p]) ----
__launch_bounds__(256)
__global__ void k_heads(const float* __restrict__ base,
                        const float* __restrict__ clsw, const float* __restrict__ regw,
                        const float* __restrict__ g2, const float* __restrict__ b2,
                        const float* __restrict__ m2, const float* __restrict__ v2,
                        const float* __restrict__ g3, const float* __restrict__ b3,
                        const float* __restrict__ m3, const float* __restrict__ v3,
                        float* __restrict__ out)
{
    __shared__ float wt[256*56];   // [ci][co<54]  (co: 0..17 cls, 18..53 reg)
    int tid = threadIdx.x;
    for (int i = tid; i < 54*256; i += 256) {
        int co = i >> 8, ci = i & 255;
        float v = (co < 18) ? clsw[i] : regw[i - 18*256];
        wt[ci*56 + co] = v;
    }
    __syncthreads();
    int gp = blockIdx.x*256 + tid;           // 0..25599
    int n = gp / PX, p = gp % PX;
    float acc[54];
    #pragma unroll
    for (int i = 0; i < 54; ++i) acc[i] = 0.f;
    const float* bp = base + (size_t)n*CIN*PX + p;
    for (int ci = 0; ci < 256; ++ci) {
        float xv = bp[(size_t)ci*PX];        // coalesced: lanes read adjacent p
        const float* wr = &wt[ci*56];
        #pragma unroll
        for (int co = 0; co < 54; ++co) acc[co] = fmaf(wr[co], xv, acc[co]);
    }
    int fgb = n*NANCH + p*NA;
    #pragma unroll
    for (int a = 0; a < NA; ++a) {
        float i0 = g2[2*a]   / sqrtf(v2[2*a]   + 1e-5f);
        float i1 = g2[2*a+1] / sqrtf(v2[2*a+1] + 1e-5f);
        float s0 = acc[2*a]*i0   + (b2[2*a]   - m2[2*a]*i0);
        float s1 = acc[2*a+1]*i1 + (b2[2*a+1] - m2[2*a+1]*i1);
        float mx = fmaxf(s0, s1);
        float e0 = expf(s0 - mx), e1 = expf(s1 - mx);
        out[fgb + a] = e1 / (e0 + e1);
    }
    size_t rb = (size_t)O_REG + (size_t)n*NANCH*4 + (size_t)p*36;
    #pragma unroll
    for (int c = 0; c < 36; ++c) {
        float iv = g3[c] / sqrtf(v3[c] + 1e-5f);
        out[rb + c] = acc[18 + c]*iv + (b3[c] - m3[c]*iv);
    }
}

// ---- decode + clip + min-size filter + sortable key (pure streaming, no atomics) ----
__global__ void k_decode(const float* __restrict__ out,
                         float* __restrict__ boxes, u32* __restrict__ keys)
{
    int gi = blockIdx.x*256 + threadIdx.x;   // 0..230399
    int n = gi / NANCH, i = gi % NANCH;
    int a = i % NA, p = i / NA;
    int wx = p % HW, hy = p / HW;
    const float4 d = *(const float4*)&out[O_REG + (size_t)n*NANCH*4 + (size_t)i*4];
    float aw = c_aw[a], ah = c_ah[a];
    float acx = 16.f + 16.f*(float)wx;
    float acy = 16.f + 16.f*(float)hy;
    float pcx = d.x*aw + acx;
    float pcy = d.y*ah + acy;
    float pw = expf(d.z)*aw;
    float ph = expf(d.w)*ah;
    float x1 = fminf(fmaxf(pcx - 0.5f*pw, 0.f), 1279.f);
    float y1 = fminf(fmaxf(pcy - 0.5f*ph, 0.f), 1279.f);
    float x2 = fminf(fmaxf(pcx + 0.5f*pw, 0.f), 1279.f);
    float y2 = fminf(fmaxf(pcy + 0.5f*ph, 0.f), 1279.f);
    float wsz = x2 - x1 + 1.f, hsz = y2 - y1 + 1.f;
    float sc = out[(size_t)n*NANCH + i];
    float s = (wsz >= 16.f && hsz >= 16.f) ? sc : -1e9f;
    *(float4*)&boxes[((size_t)n*NANCH + i)*4] = make_float4(x1, y1, x2, y2);
    u32 u = __float_as_uint(s);
    u = (u & 0x80000000u) ? ~u : (u | 0x80000000u);   // monotone order-preserving map
    keys[(size_t)n*NANCH + i] = u;
}

// ---- per-slice 12-bit histograms (LDS-only atomics, exclusive global slices) ----
__launch_bounds__(256)
__global__ void k_hist(const u32* __restrict__ keys, u32* __restrict__ ghp)
{
    __shared__ u32 hh[4096];
    int bid = blockIdx.x;              // 256 = 4 n x 64 slices
    int n = bid >> 6, slice = bid & 63;
    int tid = threadIdx.x;
    #pragma unroll
    for (int k = 0; k < 16; ++k) hh[tid + k*256] = 0;
    __syncthreads();
    const u32* kp = keys + (size_t)n*NANCH + slice*900;
    for (int i = tid; i < 900; i += 256)
        atomicAdd(&hh[kp[i] >> 20], 1u);
    __syncthreads();
    u32* gp = ghp + ((size_t)n*64 + slice)*2048;
    #pragma unroll
    for (int k = 0; k < 8; ++k) {
        int j = tid + k*256;
        gp[j] = (hh[2*j] & 0xFFFFu) | (hh[2*j+1] << 16);
    }
}

// ---- two-level (12+12 bit) radix-select + compact + adaptive bitonic -> top-1000 ----
__launch_bounds__(1024)
__global__ void k_select(const u32* __restrict__ keys, const u32* __restrict__ ghp,
                         const float* __restrict__ boxes, float* __restrict__ topbox)
{
    __shared__ u32 h1[4096];
    __shared__ u32 h2[4][4096];
    __shared__ u32 ss[1025];
    __shared__ int sB1, sA1, sB2, scnt;
    __shared__ u64 cand[CANDN];
    int n = blockIdx.x, tid = threadIdx.x, wid = tid >> 6;

    // pass 0: reduce 64 u16 slices -> h1
    const u32* gp = ghp + (size_t)n*64*2048;
    u32 c0=0,c1=0,c2=0,c3=0;
    for (int s = 0; s < 64; ++s) {
        const u32* w = gp + s*2048 + 2*tid;
        u32 a = w[0], b = w[1];
        c0 += a & 0xFFFFu; c1 += a >> 16; c2 += b & 0xFFFFu; c3 += b >> 16;
    }
    h1[4*tid+0]=c0; h1[4*tid+1]=c1; h1[4*tid+2]=c2; h1[4*tid+3]=c3;
    ss[tid] = c0+c1+c2+c3;
    if (tid == 0) scnt = 0;
    __syncthreads();
    for (int off = 1; off < 1024; off <<= 1) {   // suffix sums
        u32 v = (tid + off < 1024) ? ss[tid + off] : 0u;
        __syncthreads();
        ss[tid] += v;
        __syncthreads();
    }
    {
        u32 nxt = (tid == 1023) ? 0u : ss[tid + 1];
        if (ss[tid] >= PRE && nxt < PRE) {
            u32 c = nxt;
            for (int b = 4*tid+3; b >= 4*tid; --b) {
                c += h1[b];
                if (c >= PRE) { sB1 = b; sA1 = (int)(c - h1[b]); break; }
            }
        }
    }
    __syncthreads();
    int B1 = sB1, A1 = sA1;
    for (int k = tid; k < 4*4096; k += 1024) ((u32*)h2)[k] = 0;
    __syncthreads();

    // pass 1: emit strict-above candidates; histogram boundary bin's next 12 bits
    const u32* kp = keys + (size_t)n*NANCH;
    for (int i = tid; i < NANCH; i += 1024) {
        u32 k = kp[i];
        int top = (int)(k >> 20);
        if (top > B1) {
            int pos = atomicAdd(&scnt, 1);
            if (pos < CANDN) cand[pos] = ~(((u64)k << 32) | (u64)(0xFFFFFFFFu - (u32)i));
        } else if (top == B1) {
            atomicAdd(&h2[wid & 3][(k >> 8) & 0xFFFu], 1u);
        }
    }
    __syncthreads();
    {
        int b = 4*tid;
        u32 d0 = h2[0][b]+h2[1][b]+h2[2][b]+h2[3][b];
        u32 d1 = h2[0][b+1]+h2[1][b+1]+h2[2][b+1]+h2[3][b+1];
        u32 d2 = h2[0][b+2]+h2[1][b+2]+h2[2][b+2]+h2[3][b+2];
        u32 d3 = h2[0][b+3]+h2[1][b+3]+h2[2][b+3]+h2[3][b+3];
        ss[tid] = d0+d1+d2+d3;
    }
    __syncthreads();
    for (int off = 1; off < 1024; off <<= 1) {
        u32 v = (tid + off < 1024) ? ss[tid + off] : 0u;
        __syncthreads();
        ss[tid] += v;
        __syncthreads();
    }
    {
        u32 nxt = (tid == 1023) ? 0u : ss[tid + 1];
        if ((u32)A1 + ss[tid] >= PRE && (u32)A1 + nxt < PRE) {
            u32 c = (u32)A1 + nxt;
            for (int b = 4*tid+3; b >= 4*tid; --b) {
                u32 hv = h2[0][b]+h2[1][b]+h2[2][b]+h2[3][b];
                c += hv;
                if (c >= PRE) { sB2 = b; break; }
            }
        }
    }
    __syncthreads();
    int B2 = sB2;

    // pass 2: emit boundary-bin candidates with sub-key >= B2
    for (int i = tid; i < NANCH; i += 1024) {
        u32 k = kp[i];
        if ((int)(k >> 20) == B1 && (int)((k >> 8) & 0xFFFu) >= B2) {
            int pos = atomicAdd(&scnt, 1);
            if (pos < CANDN) cand[pos] = ~(((u64)k << 32) | (u64)(0xFFFFFFFFu - (u32)i));
        }
    }
    __syncthreads();
    int cnt = min(scnt, CANDN);
    int N = (cnt <= 2048) ? 2048 : CANDN;    // adaptive sort size (block-uniform)
    for (int i = cnt + tid; i < N; i += 1024) cand[i] = ~0ull;
    __syncthreads();
    for (int k = 2; k <= N; k <<= 1) {       // bitonic ascending = (score desc, idx asc)
        for (int j = k >> 1; j > 0; j >>= 1) {
            for (int t = tid; t < N/2; t += 1024) {
                int i1 = 2*t - (t & (j - 1));
                int i2 = i1 + j;
                u64 va = cand[i1], vb = cand[i2];
                bool up = ((i1 & k) == 0);
                if ((va > vb) == up) { cand[i1] = vb; cand[i2] = va; }
            }
            __syncthreads();
        }
    }
    for (int r = tid; r < PRE; r += 1024) {
        u64 c = ~cand[r];
        u32 idx = 0xFFFFFFFFu - (u32)(c & 0xFFFFFFFFull);
        *(float4*)&topbox[((size_t)n*PRE + r)*4] =
            *(const float4*)&boxes[((size_t)n*NANCH + idx)*4];
    }
}

// ---- IoU suppression bit-masks (64 blocks: 4 n x 16 chunks of 64 i) ----
__launch_bounds__(256)
__global__ void k_iou(const float* __restrict__ topbox, u64* __restrict__ masks)
{
    int n = blockIdx.x >> 4, chunk = blockIdx.x & 15;
    __shared__ float4 bs[PRE];
    for (int i = threadIdx.x; i < PRE; i += 256)
        bs[i] = *(const float4*)&topbox[((size_t)n*PRE + i)*4];
    __syncthreads();
    int il = threadIdx.x >> 2;          // 0..63
    int wq = threadIdx.x & 3;           // w-quarter: 4 words each
    int i = chunk*64 + il;
    if (i >= PRE) return;
    float4 bi = bs[i];
    float ai = (bi.z - bi.x + 1.f) * (bi.w - bi.y + 1.f);
    u64* mrow = masks + ((size_t)n*PRE + i)*16;
    for (int w = wq*4; w < wq*4 + 4; ++w) {
        u64 m = 0;
        int jn = min(64, PRE - w*64);
        for (int jj = 0; jj < jn; ++jj) {
            int j = w*64 + jj;
            float4 bj = bs[j];
            float xx1 = fmaxf(bi.x, bj.x);
            float yy1 = fmaxf(bi.y, bj.y);
            float xx2 = fminf(bi.z, bj.z);
            float yy2 = fminf(bi.w, bj.w);
            float iw = fmaxf(xx2 - xx1 + 1.f, 0.f);
            float ih = fmaxf(yy2 - yy1 + 1.f, 0.f);
            float inter = iw * ih;
            float aj = (bj.z - bj.x + 1.f) * (bj.w - bj.y + 1.f);
            float iou = inter / (ai + aj - inter);
            if ((j > i) && (iou > 0.7f)) m |= (1ull << jj);
        }
        mrow[w] = m;
    }
}

// ---- sequential NMS sweep (1 wave/batch, remv distributed over 16 lanes) + rois ----
__launch_bounds__(64)
__global__ void k_nms(const u64* __restrict__ masks, const float* __restrict__ topbox,
                      float* __restrict__ out)
{
    int n = blockIdx.x;
    int lane = threadIdx.x;
    int w = lane & 15;
    const u64* M = masks + (size_t)n*PRE*16;
    u64 remv = 0, keep = 0;
    u64 m0 = M[0*16+w], m1 = M[1*16+w], m2 = M[2*16+w], m3 = M[3*16+w];
    u64 m4 = M[4*16+w], m5 = M[5*16+w], m6 = M[6*16+w], m7 = M[7*16+w];
#define PROC(MR, II) { \
    int ii = (II); \
    u64 rw = __shfl(remv, ii >> 6, 64); \
    if (((rw >> (ii & 63)) & 1ull) == 0ull) { \
        remv |= MR; \
        if (w == (ii >> 6)) keep |= (1ull << (ii & 63)); \
    } }
    for (int b = 0; b < PRE; b += 8) {
        PROC(m0, b+0); m0 = (b+8  < PRE) ? M[(size_t)(b+8)*16 + w]  : 0ull;
        PROC(m1, b+1); m1 = (b+9  < PRE) ? M[(size_t)(b+9)*16 + w]  : 0ull;
        PROC(m2, b+2); m2 = (b+10 < PRE) ? M[(size_t)(b+10)*16 + w] : 0ull;
        PROC(m3, b+3); m3 = (b+11 < PRE) ? M[(size_t)(b+11)*16 + w] : 0ull;
        PROC(m4, b+4); m4 = (b+12 < PRE) ? M[(size_t)(b+12)*16 + w] : 0ull;
        PROC(m5, b+5); m5 = (b+13 < PRE) ? M[(size_t)(b+13)*16 + w] : 0ull;
        PROC(m6, b+6); m6 = (b+14 < PRE) ? M[(size_t)(b+14)*16 + w] : 0ull;
        PROC(m7, b+7); m7 = (b+15 < PRE) ? M[(size_t)(b+15)*16 + w] : 0ull;
    }
#undef PROC
    __shared__ int cnts[16];
    __shared__ int pfx[17];
    __shared__ u32 list[PRE];
    if (lane < 16) cnts[lane] = __popcll(keep);
    __syncthreads();
    if (lane == 0) {
        int s = 0;
        for (int t = 0; t < 16; ++t) { pfx[t] = s; s += cnts[t]; }
        pfx[16] = s;
    }
    __syncthreads();
    if (lane < 16) {
        int pos = pfx[lane];
        u64 kk = keep;
        for (int b = 0; b < 64; ++b)
            if ((kk >> b) & 1ull) list[pos++] = (u32)(lane*64 + b);
    }
    __syncthreads();
    int total = pfx[16];
    for (int k = lane; k < POST; k += 64) {
        float4 v = make_float4(0.f, 0.f, 0.f, 0.f);
        if (k < total) {
            u32 r = list[k];
            v = *(const float4*)&topbox[((size_t)n*PRE + r)*4];
        }
        *(float4*)&out[O_ROIS + ((size_t)n*POST + k)*4] = v;
    }
}

extern "C" void kernel_launch(void* const* d_in, const int* in_sizes, int n_in,
                              void* d_out, int out_size, void* d_ws, size_t ws_size,
                              hipStream_t stream)
{
    const float* x      = (const float*)d_in[0];
    const float* conv_w = (const float*)d_in[1];
    const float* conv_b = (const float*)d_in[2];
    const float* g1 = (const float*)d_in[3];
    const float* b1 = (const float*)d_in[4];
    const float* m1 = (const float*)d_in[5];
    const float* v1 = (const float*)d_in[6];
    const float* clsw = (const float*)d_in[7];
    const float* g2 = (const float*)d_in[8];
    const float* b2 = (const float*)d_in[9];
    const float* m2 = (const float*)d_in[10];
    const float* v2 = (const float*)d_in[11];
    const float* regw = (const float*)d_in[12];
    const float* g3 = (const float*)d_in[13];
    const float* b3 = (const float*)d_in[14];
    const float* m3 = (const float*)d_in[15];
    const float* v3 = (const float*)d_in[16];
    // d_in[17]/d_in[18] = img_h/img_w, fixed 1280 -> clip bound 1279.f hardcoded

    char* ws = (char*)d_ws;
    f16*   Wp     = (f16*)(ws + WS_WPREP);
    float* base   = (float*)(ws + WS_BASE);
    float* boxes  = (float*)(ws + WS_BOX);
    u32*   keys   = (u32*)(ws + WS_KEY);
    u32*   ghp    = (u32*)(ws + WS_GH);
    float* topbox = (float*)(ws + WS_TBOX);
    u64*   masks  = (u64*)(ws + WS_MASK);
    float* out = (float*)d_out;

    k_prepw<<<72, 256, 0, stream>>>(conv_w, Wp);
    k_conv3<<<400, 256, 0, stream>>>(x, Wp, conv_b, g1, b1, m1, v1, base);
    k_heads<<<100, 256, 0, stream>>>(base, clsw, regw, g2, b2, m2, v2, g3, b3, m3, v3, out);
    k_decode<<<900, 256, 0, stream>>>(out, boxes, keys);
    k_hist<<<256, 256, 0, stream>>>(keys, ghp);
    k_select<<<4, 1024, 0, stream>>>(keys, ghp, boxes, topbox);
    k_iou<<<64, 256, 0, stream>>>(topbox, masks);
    k_nms<<<4, 64, 0, stream>>>(masks, topbox, out);
}

// Round 12
// 465.369 us; speedup vs baseline: 1.0907x; 1.0020x over previous
//
#include <hip/hip_runtime.h>
#include <stdint.h>

typedef unsigned int u32;
typedef unsigned long long u64;
typedef _Float16 f16;
typedef __attribute__((ext_vector_type(8))) _Float16 f16x8;
typedef __attribute__((ext_vector_type(4))) float f32x4;

#define NB 4
#define CIN 256
#define HW 80
#define PX (HW*HW)            // 6400
#define NA 9
#define NANCH (PX*NA)         // 57600
#define PRE 1000
#define POST 300
#define CANDN 4096

// d_out layout (floats): fg[4*57600], rpn_reg[4*57600*4], rois[4*300*4]
#define O_REG  (NB*NANCH)             // 230400
#define O_ROIS (O_REG + NB*NANCH*4)   // 1152000

// workspace byte offsets (all 16B aligned)
#define WS_WPREP 0ull          // 9*8*2*256*40 f16 = 2949120 B
#define WS_BASE  2949120ull    // 4*256*6400 f ([n][co][p]) = 26214400 B
#define WS_BOX   29163520ull   // 4*57600*4 f  = 3686400 B
#define WS_KEY   32849920ull   // 4*57600 u32  = 921600 B
#define WS_GH    33771520ull   // 4*64*2048 u32 (u16-packed 4096 bins) = 2097152 B
#define WS_TBOX  35868672ull   // 4*1000*4 f   = 64000 B
#define WS_MASK  35932672ull   // 4*1000*16 u64= 512000 B

// anchor widths/heights (base=32, scales 8/16/32, ratios .5/1/2 with np rounding)
__constant__ float c_aw[9] = {360.f,720.f,1440.f,256.f,512.f,1024.f,184.f,368.f,736.f};
__constant__ float c_ah[9] = {176.f,352.f,704.f,256.f,512.f,1024.f,368.f,736.f,1472.f};

// ---- weight prep: fp32 w[co][ci][t] -> fp16 (h, m=residual*4096) in staging layout
// Wp[(t*8+cib)*20480 + part*10240 + co*40 + ci_local], rows padded 32->40 (80B)
__global__ void k_prepw(const float* __restrict__ w, f16* __restrict__ Wp)
{
    int id = blockIdx.x*256 + threadIdx.x;
    if (id >= 9*8*256) return;
    int co = id & 255;
    int tc = id >> 8;            // t*8+cib
    int t = tc >> 3, cib = tc & 7;
    __align__(16) f16 hb[40];
    __align__(16) f16 mb[40];
    #pragma unroll
    for (int k = 32; k < 40; ++k) { hb[k] = (f16)0.f; mb[k] = (f16)0.f; }
    #pragma unroll
    for (int ci = 0; ci < 32; ++ci) {
        float wv = w[((size_t)co*256 + (cib*32 + ci))*9 + t];
        f16 h = (f16)wv;
        f16 m = (f16)((wv - (float)h) * 4096.f);
        hb[ci] = h; mb[ci] = m;
    }
    f16* oh = Wp + (size_t)tc*20480 + (size_t)co*40;
    f16* om = oh + 10240;
    #pragma unroll
    for (int k = 0; k < 5; ++k) {
        *(f16x8*)(oh + k*8) = *(const f16x8*)(hb + k*8);
        *(f16x8*)(om + k*8) = *(const f16x8*)(mb + k*8);
    }
}

// ---- conv3x3 (implicit GEMM, fp16-split MFMA) + bias + mish + bn1 -> base (NCHW fp32)
// r2-exact (best measured: 196 us). block: 256 thr = 4 waves (2co x 2px),
// tile 128co x 128px (16w x 8h), K-step 32ci x 9 taps, 2 barriers per tap.
__launch_bounds__(256, 2)
__global__ void k_conv3(const float* __restrict__ x, const f16* __restrict__ Wp,
                        const float* __restrict__ cbias,
                        const float* __restrict__ g1, const float* __restrict__ b1,
                        const float* __restrict__ m1, const float* __restrict__ v1,
                        float* __restrict__ base)
{
    __shared__ __align__(16) f16 ldsA[10240];  // [2 part][128 co][40 (32ci+pad)]
    __shared__ __align__(16) f16 ldsX[14400];  // [2 part][180 pos][40 (32ci+pad)]
    int tid = threadIdx.x;
    int lane = tid & 63, wid = tid >> 6;
    int q = lane >> 4, l16 = lane & 15;
    int wc = (wid >> 1) * 64, wr = (wid & 1) * 4;
    int bid = blockIdx.x;
    int cb = bid & 1, pxb = bid >> 1;
    int n = pxb / 50, rem = pxb % 50;
    int h0 = (rem / 5) * 8, w0 = (rem % 5) * 16;

    f32x4 acch[4][4], accl[4][4];
    #pragma unroll
    for (int i = 0; i < 4; ++i)
        #pragma unroll
        for (int j = 0; j < 4; ++j) {
            acch[i][j] = (f32x4){0.f,0.f,0.f,0.f};
            accl[i][j] = (f32x4){0.f,0.f,0.f,0.f};
        }

    const float* xn = x + (size_t)n*CIN*PX;

    for (int cb8 = 0; cb8 < 8; ++cb8) {
        int ci0 = cb8 * 32;
        for (int t = 0; t < 9; ++t) {
            __syncthreads();                    // all waves done reading prev tiles
            if (t == 0) {
                // stage X halo: 10 rows x 18 cols x 32 ci, fp32 -> (h, m*4096) fp16
                for (int task = tid; task < 320; task += 256) {
                    int r = task >> 5, ci = task & 31;
                    int hh = h0 - 1 + r;
                    bool rowok = (hh >= 0) && (hh < HW);
                    const float* src = xn + (size_t)(ci0 + ci)*PX + hh*HW + (w0 - 1);
                    f16* dh = ldsX + r*18*40 + ci;
                    f16* dm = dh + 7200;
                    #pragma unroll
                    for (int cc = 0; cc < 18; ++cc) {
                        int ww = w0 - 1 + cc;
                        float v = (rowok && ww >= 0 && ww < HW) ? src[cc] : 0.f;
                        f16 h = (f16)v;
                        f16 m = (f16)((v - (float)h) * 4096.f);
                        dh[cc*40] = h;
                        dm[cc*40] = m;
                    }
                }
            }
            // stage A: 10240 f16 = 1280 x 16B chunks, 5 per thread, coalesced
            {
                const f16* wsrc = Wp + (size_t)(t*8 + cb8)*20480;
                #pragma unroll
                for (int c = 0; c < 5; ++c) {
                    int idx = c*256 + tid;             // 0..1279
                    int part = idx / 640, off = idx - part*640;
                    *(f16x8*)(ldsA + (size_t)idx*8) =
                        *(const f16x8*)(wsrc + part*10240 + cb*5120 + off*8);
                }
            }
            __syncthreads();                    // staging visible

            int dh_ = t / 3, dw_ = t - dh_*3;
            f16x8 Ah[4], Am[4];
            #pragma unroll
            for (int i = 0; i < 4; ++i) {
                int e = (wc + i*16 + l16)*40 + q*8;
                Ah[i] = *(const f16x8*)(ldsA + e);
                Am[i] = *(const f16x8*)(ldsA + 5120 + e);
            }
            #pragma unroll
            for (int j = 0; j < 4; ++j) {
                int pos = (wr + j + dh_)*18 + l16 + dw_;
                int e = pos*40 + q*8;
                f16x8 Bh = *(const f16x8*)(ldsX + e);
                f16x8 Bm = *(const f16x8*)(ldsX + 7200 + e);
                #pragma unroll
                for (int i = 0; i < 4; ++i) {
                    acch[i][j] = __builtin_amdgcn_mfma_f32_16x16x32_f16(Ah[i], Bh, acch[i][j], 0, 0, 0);
                    accl[i][j] = __builtin_amdgcn_mfma_f32_16x16x32_f16(Ah[i], Bm, accl[i][j], 0, 0, 0);
                    accl[i][j] = __builtin_amdgcn_mfma_f32_16x16x32_f16(Am[i], Bh, accl[i][j], 0, 0, 0);
                }
            }
        }
    }
    // epilogue: combine splits, bias + mish + bn1, store NCHW fp32 ([n][co][p])
    #pragma unroll
    for (int i = 0; i < 4; ++i) {
        #pragma unroll
        for (int rg = 0; rg < 4; ++rg) {
            int co = cb*128 + wc + i*16 + q*4 + rg;
            float cbv = cbias[co];
            float inv = g1[co] / sqrtf(v1[co] + 1e-5f);
            float ad  = b1[co] - m1[co]*inv;
            #pragma unroll
            for (int j = 0; j < 4; ++j) {
                float tval = acch[i][j][rg] + accl[i][j][rg]*(1.f/4096.f) + cbv;
                float sp = fmaxf(tval, 0.f) + log1pf(expf(-fabsf(tval)));  // softplus
                float mi = tval * tanhf(sp);                               // mish
                int h = h0 + wr + j, w = w0 + l16;
                base[(size_t)(n*CIN + co)*PX + h*HW + w] = mi*inv + ad;
            }
        }
    }
}

// ---- 1x1 heads + bn2/softmax (fg) + bn3 (rpn_reg) -> d_out (base [n][co][p]) ----
__launch_bounds__(256)
__global__ void k_heads(const float* __restrict__ base,
                        const float* __restrict__ clsw, const float* __restrict__ regw,
                        const float* __restrict__ g2, const float* __restrict__ b2,
                        const float* __restrict__ m2, const float* __restrict__ v2,
                        const float* __restrict__ g3, const float* __restrict__ b3,
                        const float* __restrict__ m3, const float* __restrict__ v3,
                        float* __restrict__ out)
{
    __shared__ float wt[256*56];   // [ci][co<54]  (co: 0..17 cls, 18..53 reg)
    int tid = threadIdx.x;
    for (int i = tid; i < 54*256; i += 256) {
        int co = i >> 8, ci = i & 255;
        float v = (co < 18) ? clsw[i] : regw[i - 18*256];
        wt[ci*56 + co] = v;
    }
    __syncthreads();
    int gp = blockIdx.x*256 + tid;           // 0..25599
    int n = gp / PX, p = gp % PX;
    float acc[54];
    #pragma unroll
    for (int i = 0; i < 54; ++i) acc[i] = 0.f;
    const float* bp = base + (size_t)n*CIN*PX + p;
    for (int ci = 0; ci < 256; ++ci) {
        float xv = bp[(size_t)ci*PX];        // coalesced: lanes read adjacent p
        const float* wr = &wt[ci*56];
        #pragma unroll
        for (int co = 0; co < 54; ++co) acc[co] = fmaf(wr[co], xv, acc[co]);
    }
    int fgb = n*NANCH + p*NA;
    #pragma unroll
    for (int a = 0; a < NA; ++a) {
        float i0 = g2[2*a]   / sqrtf(v2[2*a]   + 1e-5f);
        float i1 = g2[2*a+1] / sqrtf(v2[2*a+1] + 1e-5f);
        float s0 = acc[2*a]*i0   + (b2[2*a]   - m2[2*a]*i0);
        float s1 = acc[2*a+1]*i1 + (b2[2*a+1] - m2[2*a+1]*i1);
        float mx = fmaxf(s0, s1);
        float e0 = expf(s0 - mx), e1 = expf(s1 - mx);
        out[fgb + a] = e1 / (e0 + e1);
    }
    size_t rb = (size_t)O_REG + (size_t)n*NANCH*4 + (size_t)p*36;
    #pragma unroll
    for (int c = 0; c < 36; ++c) {
        float iv = g3[c] / sqrtf(v3[c] + 1e-5f);
        out[rb + c] = acc[18 + c]*iv + (b3[c] - m3[c]*iv);
    }
}

// ---- decode + clip + min-size filter + sortable key (pure streaming, no atomics) ----
__global__ void k_decode(const float* __restrict__ out,
                         float* __restrict__ boxes, u32* __restrict__ keys)
{
    int gi = blockIdx.x*256 + threadIdx.x;   // 0..230399
    int n = gi / NANCH, i = gi % NANCH;
    int a = i % NA, p = i / NA;
    int wx = p % HW, hy = p / HW;
    const float4 d = *(const float4*)&out[O_REG + (size_t)n*NANCH*4 + (size_t)i*4];
    float aw = c_aw[a], ah = c_ah[a];
    float acx = 16.f + 16.f*(float)wx;
    float acy = 16.f + 16.f*(float)hy;
    float pcx = d.x*aw + acx;
    float pcy = d.y*ah + acy;
    float pw = expf(d.z)*aw;
    float ph = expf(d.w)*ah;
    float x1 = fminf(fmaxf(pcx - 0.5f*pw, 0.f), 1279.f);
    float y1 = fminf(fmaxf(pcy - 0.5f*ph, 0.f), 1279.f);
    float x2 = fminf(fmaxf(pcx + 0.5f*pw, 0.f), 1279.f);
    float y2 = fminf(fmaxf(pcy + 0.5f*ph, 0.f), 1279.f);
    float wsz = x2 - x1 + 1.f, hsz = y2 - y1 + 1.f;
    float sc = out[(size_t)n*NANCH + i];
    float s = (wsz >= 16.f && hsz >= 16.f) ? sc : -1e9f;
    *(float4*)&boxes[((size_t)n*NANCH + i)*4] = make_float4(x1, y1, x2, y2);
    u32 u = __float_as_uint(s);
    u = (u & 0x80000000u) ? ~u : (u | 0x80000000u);   // monotone order-preserving map
    keys[(size_t)n*NANCH + i] = u;
}

// ---- per-slice 12-bit histograms (LDS-only atomics, exclusive global slices) ----
__launch_bounds__(256)
__global__ void k_hist(const u32* __restrict__ keys, u32* __restrict__ ghp)
{
    __shared__ u32 hh[4096];
    int bid = blockIdx.x;              // 256 = 4 n x 64 slices
    int n = bid >> 6, slice = bid & 63;
    int tid = threadIdx.x;
    #pragma unroll
    for (int k = 0; k < 16; ++k) hh[tid + k*256] = 0;
    __syncthreads();
    const u32* kp = keys + (size_t)n*NANCH + slice*900;
    for (int i = tid; i < 900; i += 256)
        atomicAdd(&hh[kp[i] >> 20], 1u);
    __syncthreads();
    u32* gp = ghp + ((size_t)n*64 + slice)*2048;
    #pragma unroll
    for (int k = 0; k < 8; ++k) {
        int j = tid + k*256;
        gp[j] = (hh[2*j] & 0xFFFFu) | (hh[2*j+1] << 16);
    }
}

// ---- two-level (12+12 bit) radix-select + compact + adaptive bitonic -> top-1000 ----
__launch_bounds__(1024)
__global__ void k_select(const u32* __restrict__ keys, const u32* __restrict__ ghp,
                         const float* __restrict__ boxes, float* __restrict__ topbox)
{
    __shared__ u32 h1[4096];
    __shared__ u32 h2[4][4096];
    __shared__ u32 ss[1025];
    __shared__ int sB1, sA1, sB2, scnt;
    __shared__ u64 cand[CANDN];
    int n = blockIdx.x, tid = threadIdx.x, wid = tid >> 6;

    // pass 0: reduce 64 u16 slices -> h1
    const u32* gp = ghp + (size_t)n*64*2048;
    u32 c0=0,c1=0,c2=0,c3=0;
    for (int s = 0; s < 64; ++s) {
        const u32* w = gp + s*2048 + 2*tid;
        u32 a = w[0], b = w[1];
        c0 += a & 0xFFFFu; c1 += a >> 16; c2 += b & 0xFFFFu; c3 += b >> 16;
    }
    h1[4*tid+0]=c0; h1[4*tid+1]=c1; h1[4*tid+2]=c2; h1[4*tid+3]=c3;
    ss[tid] = c0+c1+c2+c3;
    if (tid == 0) scnt = 0;
    __syncthreads();
    for (int off = 1; off < 1024; off <<= 1) {   // suffix sums
        u32 v = (tid + off < 1024) ? ss[tid + off] : 0u;
        __syncthreads();
        ss[tid] += v;
        __syncthreads();
    }
    {
        u32 nxt = (tid == 1023) ? 0u : ss[tid + 1];
        if (ss[tid] >= PRE && nxt < PRE) {
            u32 c = nxt;
            for (int b = 4*tid+3; b >= 4*tid; --b) {
                c += h1[b];
                if (c >= PRE) { sB1 = b; sA1 = (int)(c - h1[b]); break; }
            }
        }
    }
    __syncthreads();
    int B1 = sB1, A1 = sA1;
    for (int k = tid; k < 4*4096; k += 1024) ((u32*)h2)[k] = 0;
    __syncthreads();

    // pass 1: emit strict-above candidates; histogram boundary bin's next 12 bits
    const u32* kp = keys + (size_t)n*NANCH;
    for (int i = tid; i < NANCH; i += 1024) {
        u32 k = kp[i];
        int top = (int)(k >> 20);
        if (top > B1) {
            int pos = atomicAdd(&scnt, 1);
            if (pos < CANDN) cand[pos] = ~(((u64)k << 32) | (u64)(0xFFFFFFFFu - (u32)i));
        } else if (top == B1) {
            atomicAdd(&h2[wid & 3][(k >> 8) & 0xFFFu], 1u);
        }
    }
    __syncthreads();
    {
        int b = 4*tid;
        u32 d0 = h2[0][b]+h2[1][b]+h2[2][b]+h2[3][b];
        u32 d1 = h2[0][b+1]+h2[1][b+1]+h2[2][b+1]+h2[3][b+1];
        u32 d2 = h2[0][b+2]+h2[1][b+2]+h2[2][b+2]+h2[3][b+2];
        u32 d3 = h2[0][b+3]+h2[1][b+3]+h2[2][b+3]+h2[3][b+3];
        ss[tid] = d0+d1+d2+d3;
    }
    __syncthreads();
    for (int off = 1; off < 1024; off <<= 1) {
        u32 v = (tid + off < 1024) ? ss[tid + off] : 0u;
        __syncthreads();
        ss[tid] += v;
        __syncthreads();
    }
    {
        u32 nxt = (tid == 1023) ? 0u : ss[tid + 1];
        if ((u32)A1 + ss[tid] >= PRE && (u32)A1 + nxt < PRE) {
            u32 c = (u32)A1 + nxt;
            for (int b = 4*tid+3; b >= 4*tid; --b) {
                u32 hv = h2[0][b]+h2[1][b]+h2[2][b]+h2[3][b];
                c += hv;
                if (c >= PRE) { sB2 = b; break; }
            }
        }
    }
    __syncthreads();
    int B2 = sB2;

    // pass 2: emit boundary-bin candidates with sub-key >= B2
    for (int i = tid; i < NANCH; i += 1024) {
        u32 k = kp[i];
        if ((int)(k >> 20) == B1 && (int)((k >> 8) & 0xFFFu) >= B2) {
            int pos = atomicAdd(&scnt, 1);
            if (pos < CANDN) cand[pos] = ~(((u64)k << 32) | (u64)(0xFFFFFFFFu - (u32)i));
        }
    }
    __syncthreads();
    int cnt = min(scnt, CANDN);
    int N = (cnt <= 2048) ? 2048 : CANDN;    // adaptive sort size (block-uniform)
    for (int i = cnt + tid; i < N; i += 1024) cand[i] = ~0ull;
    __syncthreads();
    for (int k = 2; k <= N; k <<= 1) {       // bitonic ascending = (score desc, idx asc)
        for (int j = k >> 1; j > 0; j >>= 1) {
            for (int t = tid; t < N/2; t += 1024) {
                int i1 = 2*t - (t & (j - 1));
                int i2 = i1 + j;
                u64 va = cand[i1], vb = cand[i2];
                bool up = ((i1 & k) == 0);
                if ((va > vb) == up) { cand[i1] = vb; cand[i2] = va; }
            }
            __syncthreads();
        }
    }
    for (int r = tid; r < PRE; r += 1024) {
        u64 c = ~cand[r];
        u32 idx = 0xFFFFFFFFu - (u32)(c & 0xFFFFFFFFull);
        *(float4*)&topbox[((size_t)n*PRE + r)*4] =
            *(const float4*)&boxes[((size_t)n*NANCH + idx)*4];
    }
}

// ---- IoU suppression bit-masks (64 blocks: 4 n x 16 chunks of 64 i) ----
__launch_bounds__(256)
__global__ void k_iou(const float* __restrict__ topbox, u64* __restrict__ masks)
{
    int n = blockIdx.x >> 4, chunk = blockIdx.x & 15;
    __shared__ float4 bs[PRE];
    for (int i = threadIdx.x; i < PRE; i += 256)
        bs[i] = *(const float4*)&topbox[((size_t)n*PRE + i)*4];
    __syncthreads();
    int il = threadIdx.x >> 2;          // 0..63
    int wq = threadIdx.x & 3;           // w-quarter: 4 words each
    int i = chunk*64 + il;
    if (i >= PRE) return;
    float4 bi = bs[i];
    float ai = (bi.z - bi.x + 1.f) * (bi.w - bi.y + 1.f);
    u64* mrow = masks + ((size_t)n*PRE + i)*16;
    for (int w = wq*4; w < wq*4 + 4; ++w) {
        u64 m = 0;
        int jn = min(64, PRE - w*64);
        for (int jj = 0; jj < jn; ++jj) {
            int j = w*64 + jj;
            float4 bj = bs[j];
            float xx1 = fmaxf(bi.x, bj.x);
            float yy1 = fmaxf(bi.y, bj.y);
            float xx2 = fminf(bi.z, bj.z);
            float yy2 = fminf(bi.w, bj.w);
            float iw = fmaxf(xx2 - xx1 + 1.f, 0.f);
            float ih = fmaxf(yy2 - yy1 + 1.f, 0.f);
            float inter = iw * ih;
            float aj = (bj.z - bj.x + 1.f) * (bj.w - bj.y + 1.f);
            float iou = inter / (ai + aj - inter);
            if ((j > i) && (iou > 0.7f)) m |= (1ull << jj);
        }
        mrow[w] = m;
    }
}

// ---- sequential NMS sweep (1 wave/batch, remv distributed over 16 lanes) + rois ----
__launch_bounds__(64)
__global__ void k_nms(const u64* __restrict__ masks, const float* __restrict__ topbox,
                      float* __restrict__ out)
{
    int n = blockIdx.x;
    int lane = threadIdx.x;
    int w = lane & 15;
    const u64* M = masks + (size_t)n*PRE*16;
    u64 remv = 0, keep = 0;
    u64 m0 = M[0*16+w], m1 = M[1*16+w], m2 = M[2*16+w], m3 = M[3*16+w];
    u64 m4 = M[4*16+w], m5 = M[5*16+w], m6 = M[6*16+w], m7 = M[7*16+w];
#define PROC(MR, II) { \
    int ii = (II); \
    u64 rw = __shfl(remv, ii >> 6, 64); \
    if (((rw >> (ii & 63)) & 1ull) == 0ull) { \
        remv |= MR; \
        if (w == (ii >> 6)) keep |= (1ull << (ii & 63)); \
    } }
    for (int b = 0; b < PRE; b += 8) {
        PROC(m0, b+0); m0 = (b+8  < PRE) ? M[(size_t)(b+8)*16 + w]  : 0ull;
        PROC(m1, b+1); m1 = (b+9  < PRE) ? M[(size_t)(b+9)*16 + w]  : 0ull;
        PROC(m2, b+2); m2 = (b+10 < PRE) ? M[(size_t)(b+10)*16 + w] : 0ull;
        PROC(m3, b+3); m3 = (b+11 < PRE) ? M[(size_t)(b+11)*16 + w] : 0ull;
        PROC(m4, b+4); m4 = (b+12 < PRE) ? M[(size_t)(b+12)*16 + w] : 0ull;
        PROC(m5, b+5); m5 = (b+13 < PRE) ? M[(size_t)(b+13)*16 + w] : 0ull;
        PROC(m6, b+6); m6 = (b+14 < PRE) ? M[(size_t)(b+14)*16 + w] : 0ull;
        PROC(m7, b+7); m7 = (b+15 < PRE) ? M[(size_t)(b+15)*16 + w] : 0ull;
    }
#undef PROC
    __shared__ int cnts[16];
    __shared__ int pfx[17];
    __shared__ u32 list[PRE];
    if (lane < 16) cnts[lane] = __popcll(keep);
    __syncthreads();
    if (lane == 0) {
        int s = 0;
        for (int t = 0; t < 16; ++t) { pfx[t] = s; s += cnts[t]; }
        pfx[16] = s;
    }
    __syncthreads();
    if (lane < 16) {
        int pos = pfx[lane];
        u64 kk = keep;
        for (int b = 0; b < 64; ++b)
            if ((kk >> b) & 1ull) list[pos++] = (u32)(lane*64 + b);
    }
    __syncthreads();
    int total = pfx[16];
    for (int k = lane; k < POST; k += 64) {
        float4 v = make_float4(0.f, 0.f, 0.f, 0.f);
        if (k < total) {
            u32 r = list[k];
            v = *(const float4*)&topbox[((size_t)n*PRE + r)*4];
        }
        *(float4*)&out[O_ROIS + ((size_t)n*POST + k)*4] = v;
    }
}

extern "C" void kernel_launch(void* const* d_in, const int* in_sizes, int n_in,
                              void* d_out, int out_size, void* d_ws, size_t ws_size,
                              hipStream_t stream)
{
    const float* x      = (const float*)d_in[0];
    const float* conv_w = (const float*)d_in[1];
    const float* conv_b = (const float*)d_in[2];
    const float* g1 = (const float*)d_in[3];
    const float* b1 = (const float*)d_in[4];
    const float* m1 = (const float*)d_in[5];
    const float* v1 = (const float*)d_in[6];
    const float* clsw = (const float*)d_in[7];
    const float* g2 = (const float*)d_in[8];
    const float* b2 = (const float*)d_in[9];
    const float* m2 = (const float*)d_in[10];
    const float* v2 = (const float*)d_in[11];
    const float* regw = (const float*)d_in[12];
    const float* g3 = (const float*)d_in[13];
    const float* b3 = (const float*)d_in[14];
    const float* m3 = (const float*)d_in[15];
    const float* v3 = (const float*)d_in[16];
    // d_in[17]/d_in[18] = img_h/img_w, fixed 1280 -> clip bound 1279.f hardcoded

    char* ws = (char*)d_ws;
    f16*   Wp     = (f16*)(ws + WS_WPREP);
    float* base   = (float*)(ws + WS_BASE);
    float* boxes  = (float*)(ws + WS_BOX);
    u32*   keys   = (u32*)(ws + WS_KEY);
    u32*   ghp    = (u32*)(ws + WS_GH);
    float* topbox = (float*)(ws + WS_TBOX);
    u64*   masks  = (u64*)(ws + WS_MASK);
    float* out = (float*)d_out;

    k_prepw<<<72, 256, 0, stream>>>(conv_w, Wp);
    k_conv3<<<400, 256, 0, stream>>>(x, Wp, conv_b, g1, b1, m1, v1, base);
    k_heads<<<100, 256, 0, stream>>>(base, clsw, regw, g2, b2, m2, v2, g3, b3, m3, v3, out);
    k_decode<<<900, 256, 0, stream>>>(out, boxes, keys);
    k_hist<<<256, 256, 0, stream>>>(keys, ghp);
    k_select<<<4, 1024, 0, stream>>>(keys, ghp, boxes, topbox);
    k_iou<<<64, 256, 0, stream>>>(topbox, masks);
    k_nms<<<4, 64, 0, stream>>>(masks, topbox, out);
}

// Round 13
// 455.735 us; speedup vs baseline: 1.1138x; 1.0211x over previous
//
#include <hip/hip_runtime.h>
#include <stdint.h>

typedef unsigned int u32;
typedef unsigned long long u64;
typedef _Float16 f16;
typedef __attribute__((ext_vector_type(8))) _Float16 f16x8;
typedef __attribute__((ext_vector_type(4))) float f32x4;

#define NB 4
#define CIN 256
#define HW 80
#define PX (HW*HW)            // 6400
#define NA 9
#define NANCH (PX*NA)         // 57600
#define PRE 1000
#define POST 300
#define CANDN 4096

// d_out layout (floats): fg[4*57600], rpn_reg[4*57600*4], rois[4*300*4]
#define O_REG  (NB*NANCH)             // 230400
#define O_ROIS (O_REG + NB*NANCH*4)   // 1152000

// workspace byte offsets (all 16B aligned)
#define WS_WPREP 0ull          // 9*8*2*256*40 f16 = 2949120 B
#define WS_BASE  2949120ull    // 4*256*6400 f ([n][co][p]) = 26214400 B
#define WS_BOX   29163520ull   // 4*57600*4 f  = 3686400 B
#define WS_KEY   32849920ull   // 4*57600 u32  = 921600 B
#define WS_GH    33771520ull   // 4*25*2048 u32 (u16-packed 4096 bins) = 819200 B
#define WS_TBOX  35868672ull   // 4*1000*4 f   = 64000 B
#define WS_MASK  35932672ull   // 4*1000*16 u64= 512000 B

// anchor widths/heights (base=32, scales 8/16/32, ratios .5/1/2 with np rounding)
__constant__ float c_aw[9] = {360.f,720.f,1440.f,256.f,512.f,1024.f,184.f,368.f,736.f};
__constant__ float c_ah[9] = {176.f,352.f,704.f,256.f,512.f,1024.f,368.f,736.f,1472.f};

// ---- weight prep: fp32 w[co][ci][t] -> fp16 (h, m=residual*4096) in staging layout
// Wp[(t*8+cib)*20480 + part*10240 + co*40 + ci_local], rows padded 32->40 (80B)
__global__ void k_prepw(const float* __restrict__ w, f16* __restrict__ Wp)
{
    int id = blockIdx.x*256 + threadIdx.x;
    if (id >= 9*8*256) return;
    int co = id & 255;
    int tc = id >> 8;            // t*8+cib
    int t = tc >> 3, cib = tc & 7;
    __align__(16) f16 hb[40];
    __align__(16) f16 mb[40];
    #pragma unroll
    for (int k = 32; k < 40; ++k) { hb[k] = (f16)0.f; mb[k] = (f16)0.f; }
    #pragma unroll
    for (int ci = 0; ci < 32; ++ci) {
        float wv = w[((size_t)co*256 + (cib*32 + ci))*9 + t];
        f16 h = (f16)wv;
        f16 m = (f16)((wv - (float)h) * 4096.f);
        hb[ci] = h; mb[ci] = m;
    }
    f16* oh = Wp + (size_t)tc*20480 + (size_t)co*40;
    f16* om = oh + 10240;
    #pragma unroll
    for (int k = 0; k < 5; ++k) {
        *(f16x8*)(oh + k*8) = *(const f16x8*)(hb + k*8);
        *(f16x8*)(om + k*8) = *(const f16x8*)(mb + k*8);
    }
}

// ---- conv3x3 (implicit GEMM, fp16-split MFMA) + bias + mish + bn1 -> base (NCHW fp32)
// r2 sync structure (2 barriers/tap), retiled 128co->64co quarters for occupancy:
// 800 blocks (4 co-quarters x 200 px-tiles), LDS 39KB -> 3 blocks/CU resident,
// ~12 waves/CU (vs 6.25 at r2's 400 blocks). Wave = 32co x 64px.
__launch_bounds__(256, 3)
__global__ void k_conv3(const float* __restrict__ x, const f16* __restrict__ Wp,
                        const float* __restrict__ cbias,
                        const float* __restrict__ g1, const float* __restrict__ b1,
                        const float* __restrict__ m1, const float* __restrict__ v1,
                        float* __restrict__ base)
{
    __shared__ __align__(16) f16 ldsA[5120];   // [2 part][64 co][40 (32ci+pad)]
    __shared__ __align__(16) f16 ldsX[14400];  // [2 part][180 pos][40]
    int tid = threadIdx.x;
    int lane = tid & 63, wid = tid >> 6;
    int q = lane >> 4, l16 = lane & 15;
    int wc = (wid >> 1) * 32, wr = (wid & 1) * 4;
    int virt = (blockIdx.x & 7)*100 + (blockIdx.x >> 3);  // XCD-chunked (800%8==0)
    int cb = virt & 3, pxb = virt >> 2;                   // co-quarter
    int n = pxb / 50, rem = pxb % 50;
    int h0 = (rem / 5) * 8, w0 = (rem % 5) * 16;

    f32x4 acch[2][4], accl[2][4];
    #pragma unroll
    for (int i = 0; i < 2; ++i)
        #pragma unroll
        for (int j = 0; j < 4; ++j) {
            acch[i][j] = (f32x4){0.f,0.f,0.f,0.f};
            accl[i][j] = (f32x4){0.f,0.f,0.f,0.f};
        }

    const float* xn = x + (size_t)n*CIN*PX;

    for (int cb8 = 0; cb8 < 8; ++cb8) {
        int ci0 = cb8 * 32;
        for (int t = 0; t < 9; ++t) {
            __syncthreads();                    // all waves done reading prev tiles
            if (t == 0) {
                // stage X halo: 10 rows x 18 cols x 32 ci, fp32 -> (h, m*4096) fp16
                for (int task = tid; task < 320; task += 256) {
                    int r = task >> 5, ci = task & 31;
                    int hh = h0 - 1 + r;
                    bool rowok = (hh >= 0) && (hh < HW);
                    const float* src = xn + (size_t)(ci0 + ci)*PX + hh*HW + (w0 - 1);
                    f16* dh = ldsX + r*18*40 + ci;
                    f16* dm = dh + 7200;
                    #pragma unroll
                    for (int cc = 0; cc < 18; ++cc) {
                        int ww = w0 - 1 + cc;
                        float v = (rowok && ww >= 0 && ww < HW) ? src[cc] : 0.f;
                        f16 h = (f16)v;
                        f16 m = (f16)((v - (float)h) * 4096.f);
                        dh[cc*40] = h;
                        dm[cc*40] = m;
                    }
                }
            }
            // stage A: 5120 f16 = 640 x8-chunks (64-co quarter, h then m part)
            {
                const f16* wsrc = Wp + (size_t)(t*8 + cb8)*20480;
                #pragma unroll
                for (int c = 0; c < 3; ++c) {
                    int idx = c*256 + tid;
                    if (idx < 640) {
                        int part = idx / 320, off = idx - part*320;
                        *(f16x8*)(ldsA + (size_t)idx*8) =
                            *(const f16x8*)(wsrc + part*10240 + cb*2560 + off*8);
                    }
                }
            }
            __syncthreads();                    // staging visible

            int dh_ = t / 3, dw_ = t - dh_*3;
            f16x8 Ah[2], Am[2];
            #pragma unroll
            for (int i = 0; i < 2; ++i) {
                int e = (wc + i*16 + l16)*40 + q*8;
                Ah[i] = *(const f16x8*)(ldsA + e);
                Am[i] = *(const f16x8*)(ldsA + 2560 + e);
            }
            #pragma unroll
            for (int j = 0; j < 4; ++j) {
                int pos = (wr + j + dh_)*18 + l16 + dw_;
                int e = pos*40 + q*8;
                f16x8 Bh = *(const f16x8*)(ldsX + e);
                f16x8 Bm = *(const f16x8*)(ldsX + 7200 + e);
                #pragma unroll
                for (int i = 0; i < 2; ++i) {
                    acch[i][j] = __builtin_amdgcn_mfma_f32_16x16x32_f16(Ah[i], Bh, acch[i][j], 0, 0, 0);
                    accl[i][j] = __builtin_amdgcn_mfma_f32_16x16x32_f16(Ah[i], Bm, accl[i][j], 0, 0, 0);
                    accl[i][j] = __builtin_amdgcn_mfma_f32_16x16x32_f16(Am[i], Bh, accl[i][j], 0, 0, 0);
                }
            }
        }
    }
    // epilogue: combine splits, bias + mish + bn1, store NCHW fp32 ([n][co][p])
    #pragma unroll
    for (int i = 0; i < 2; ++i) {
        #pragma unroll
        for (int rg = 0; rg < 4; ++rg) {
            int co = cb*64 + wc + i*16 + q*4 + rg;
            float cbv = cbias[co];
            float inv = g1[co] / sqrtf(v1[co] + 1e-5f);
            float ad  = b1[co] - m1[co]*inv;
            #pragma unroll
            for (int j = 0; j < 4; ++j) {
                float tval = acch[i][j][rg] + accl[i][j][rg]*(1.f/4096.f) + cbv;
                float sp = fmaxf(tval, 0.f) + log1pf(expf(-fabsf(tval)));  // softplus
                float mi = tval * tanhf(sp);                               // mish
                int h = h0 + wr + j, w = w0 + l16;
                base[(size_t)(n*CIN + co)*PX + h*HW + w] = mi*inv + ad;
            }
        }
    }
}

// ---- FUSED: 1x1 heads + bn2/softmax + bn3 + decode + key + LDS hist ----
// 100 blocks x 256 thr; block = 256 px of one n (6400/256=25 blocks/n).
// reg/fg stay in registers -> decode is bit-exact vs separate kernels.
__launch_bounds__(256)
__global__ void k_heads(const float* __restrict__ base,
                        const float* __restrict__ clsw, const float* __restrict__ regw,
                        const float* __restrict__ g2, const float* __restrict__ b2,
                        const float* __restrict__ m2, const float* __restrict__ v2,
                        const float* __restrict__ g3, const float* __restrict__ b3,
                        const float* __restrict__ m3, const float* __restrict__ v3,
                        float* __restrict__ out, float* __restrict__ boxes,
                        u32* __restrict__ keys, u32* __restrict__ ghp)
{
    __shared__ float wt[256*56];   // [ci][co<54]  (co: 0..17 cls, 18..53 reg)
    __shared__ u32 hh[4096];
    int tid = threadIdx.x;
    for (int i = tid; i < 54*256; i += 256) {
        int co = i >> 8, ci = i & 255;
        float v = (co < 18) ? clsw[i] : regw[i - 18*256];
        wt[ci*56 + co] = v;
    }
    #pragma unroll
    for (int k = 0; k < 16; ++k) hh[tid + k*256] = 0;
    __syncthreads();
    int gp = blockIdx.x*256 + tid;           // 0..25599
    int n = gp / PX, p = gp % PX;
    float acc[54];
    #pragma unroll
    for (int i = 0; i < 54; ++i) acc[i] = 0.f;
    const float* bp = base + (size_t)n*CIN*PX + p;
    for (int ci = 0; ci < 256; ++ci) {
        float xv = bp[(size_t)ci*PX];        // coalesced: lanes read adjacent p
        const float* wr = &wt[ci*56];
        #pragma unroll
        for (int co = 0; co < 54; ++co) acc[co] = fmaf(wr[co], xv, acc[co]);
    }
    // fg (softmax) — keep in regs for decode
    float fgv[9];
    int fgb = n*NANCH + p*NA;
    #pragma unroll
    for (int a = 0; a < NA; ++a) {
        float i0 = g2[2*a]   / sqrtf(v2[2*a]   + 1e-5f);
        float i1 = g2[2*a+1] / sqrtf(v2[2*a+1] + 1e-5f);
        float s0 = acc[2*a]*i0   + (b2[2*a]   - m2[2*a]*i0);
        float s1 = acc[2*a+1]*i1 + (b2[2*a+1] - m2[2*a+1]*i1);
        float mx = fmaxf(s0, s1);
        float e0 = expf(s0 - mx), e1 = expf(s1 - mx);
        fgv[a] = e1 / (e0 + e1);
        out[fgb + a] = fgv[a];
    }
    // reg (bn3) — keep in regs for decode
    float regv[36];
    size_t rb = (size_t)O_REG + (size_t)n*NANCH*4 + (size_t)p*36;
    #pragma unroll
    for (int c = 0; c < 36; ++c) {
        float iv = g3[c] / sqrtf(v3[c] + 1e-5f);
        regv[c] = acc[18 + c]*iv + (b3[c] - m3[c]*iv);
        out[rb + c] = regv[c];
    }
    // decode + clip + min-size + sortable key + LDS hist
    int wx = p % HW, hy = p / HW;
    float acx = 16.f + 16.f*(float)wx;
    float acy = 16.f + 16.f*(float)hy;
    #pragma unroll
    for (int a = 0; a < NA; ++a) {
        float aw = c_aw[a], ah = c_ah[a];
        float pcx = regv[4*a+0]*aw + acx;
        float pcy = regv[4*a+1]*ah + acy;
        float pw = expf(regv[4*a+2])*aw;
        float ph = expf(regv[4*a+3])*ah;
        float x1 = fminf(fmaxf(pcx - 0.5f*pw, 0.f), 1279.f);
        float y1 = fminf(fmaxf(pcy - 0.5f*ph, 0.f), 1279.f);
        float x2 = fminf(fmaxf(pcx + 0.5f*pw, 0.f), 1279.f);
        float y2 = fminf(fmaxf(pcy + 0.5f*ph, 0.f), 1279.f);
        float wsz = x2 - x1 + 1.f, hsz = y2 - y1 + 1.f;
        float s = (wsz >= 16.f && hsz >= 16.f) ? fgv[a] : -1e9f;
        int i = p*NA + a;
        *(float4*)&boxes[((size_t)n*NANCH + i)*4] = make_float4(x1, y1, x2, y2);
        u32 u = __float_as_uint(s);
        u = (u & 0x80000000u) ? ~u : (u | 0x80000000u);
        keys[(size_t)n*NANCH + i] = u;
        atomicAdd(&hh[u >> 20], 1u);
    }
    __syncthreads();
    // pack block-local hist (u16 x2 per u32); slice = blk%25
    u32* gp2 = ghp + ((size_t)n*25 + (blockIdx.x % 25))*2048;
    #pragma unroll
    for (int k = 0; k < 8; ++k) {
        int j = tid + k*256;
        gp2[j] = (hh[2*j] & 0xFFFFu) | (hh[2*j+1] << 16);
    }
}

// ---- two-level (12+12 bit) radix-select + compact + adaptive bitonic -> top-1000 ----
__launch_bounds__(1024)
__global__ void k_select(const u32* __restrict__ keys, const u32* __restrict__ ghp,
                         const float* __restrict__ boxes, float* __restrict__ topbox)
{
    __shared__ u32 h1[4096];
    __shared__ u32 h2[4][4096];
    __shared__ u32 ss[1025];
    __shared__ int sB1, sA1, sB2, scnt;
    __shared__ u64 cand[CANDN];
    int n = blockIdx.x, tid = threadIdx.x, wid = tid >> 6;

    // pass 0: reduce 25 u16 slices -> h1
    const u32* gp = ghp + (size_t)n*25*2048;
    u32 c0=0,c1=0,c2=0,c3=0;
    for (int s = 0; s < 25; ++s) {
        const u32* w = gp + s*2048 + 2*tid;
        u32 a = w[0], b = w[1];
        c0 += a & 0xFFFFu; c1 += a >> 16; c2 += b & 0xFFFFu; c3 += b >> 16;
    }
    h1[4*tid+0]=c0; h1[4*tid+1]=c1; h1[4*tid+2]=c2; h1[4*tid+3]=c3;
    ss[tid] = c0+c1+c2+c3;
    if (tid == 0) scnt = 0;
    __syncthreads();
    for (int off = 1; off < 1024; off <<= 1) {   // suffix sums
        u32 v = (tid + off < 1024) ? ss[tid + off] : 0u;
        __syncthreads();
        ss[tid] += v;
        __syncthreads();
    }
    {
        u32 nxt = (tid == 1023) ? 0u : ss[tid + 1];
        if (ss[tid] >= PRE && nxt < PRE) {
            u32 c = nxt;
            for (int b = 4*tid+3; b >= 4*tid; --b) {
                c += h1[b];
                if (c >= PRE) { sB1 = b; sA1 = (int)(c - h1[b]); break; }
            }
        }
    }
    __syncthreads();
    int B1 = sB1, A1 = sA1;
    for (int k = tid; k < 4*4096; k += 1024) ((u32*)h2)[k] = 0;
    __syncthreads();

    // pass 1: emit strict-above candidates; histogram boundary bin's next 12 bits
    const u32* kp = keys + (size_t)n*NANCH;
    for (int i = tid; i < NANCH; i += 1024) {
        u32 k = kp[i];
        int top = (int)(k >> 20);
        if (top > B1) {
            int pos = atomicAdd(&scnt, 1);
            if (pos < CANDN) cand[pos] = ~(((u64)k << 32) | (u64)(0xFFFFFFFFu - (u32)i));
        } else if (top == B1) {
            atomicAdd(&h2[wid & 3][(k >> 8) & 0xFFFu], 1u);
        }
    }
    __syncthreads();
    {
        int b = 4*tid;
        u32 d0 = h2[0][b]+h2[1][b]+h2[2][b]+h2[3][b];
        u32 d1 = h2[0][b+1]+h2[1][b+1]+h2[2][b+1]+h2[3][b+1];
        u32 d2 = h2[0][b+2]+h2[1][b+2]+h2[2][b+2]+h2[3][b+2];
        u32 d3 = h2[0][b+3]+h2[1][b+3]+h2[2][b+3]+h2[3][b+3];
        ss[tid] = d0+d1+d2+d3;
    }
    __syncthreads();
    for (int off = 1; off < 1024; off <<= 1) {
        u32 v = (tid + off < 1024) ? ss[tid + off] : 0u;
        __syncthreads();
        ss[tid] += v;
        __syncthreads();
    }
    {
        u32 nxt = (tid == 1023) ? 0u : ss[tid + 1];
        if ((u32)A1 + ss[tid] >= PRE && (u32)A1 + nxt < PRE) {
            u32 c = (u32)A1 + nxt;
            for (int b = 4*tid+3; b >= 4*tid; --b) {
                u32 hv = h2[0][b]+h2[1][b]+h2[2][b]+h2[3][b];
                c += hv;
                if (c >= PRE) { sB2 = b; break; }
            }
        }
    }
    __syncthreads();
    int B2 = sB2;

    // pass 2: emit boundary-bin candidates with sub-key >= B2
    for (int i = tid; i < NANCH; i += 1024) {
        u32 k = kp[i];
        if ((int)(k >> 20) == B1 && (int)((k >> 8) & 0xFFFu) >= B2) {
            int pos = atomicAdd(&scnt, 1);
            if (pos < CANDN) cand[pos] = ~(((u64)k << 32) | (u64)(0xFFFFFFFFu - (u32)i));
        }
    }
    __syncthreads();
    int cnt = min(scnt, CANDN);
    int N = (cnt <= 2048) ? 2048 : CANDN;    // adaptive sort size (block-uniform)
    for (int i = cnt + tid; i < N; i += 1024) cand[i] = ~0ull;
    __syncthreads();
    for (int k = 2; k <= N; k <<= 1) {       // bitonic ascending = (score desc, idx asc)
        for (int j = k >> 1; j > 0; j >>= 1) {
            for (int t = tid; t < N/2; t += 1024) {
                int i1 = 2*t - (t & (j - 1));
                int i2 = i1 + j;
                u64 va = cand[i1], vb = cand[i2];
                bool up = ((i1 & k) == 0);
                if ((va > vb) == up) { cand[i1] = vb; cand[i2] = va; }
            }
            __syncthreads();
        }
    }
    for (int r = tid; r < PRE; r += 1024) {
        u64 c = ~cand[r];
        u32 idx = 0xFFFFFFFFu - (u32)(c & 0xFFFFFFFFull);
        *(float4*)&topbox[((size_t)n*PRE + r)*4] =
            *(const float4*)&boxes[((size_t)n*NANCH + idx)*4];
    }
}

// ---- IoU suppression bit-masks (252 blocks: 4 n x 63 chunks of 16 rows; 1 word/thr) ----
__launch_bounds__(256)
__global__ void k_iou(const float* __restrict__ topbox, u64* __restrict__ masks)
{
    int n = blockIdx.x / 63, chunk = blockIdx.x % 63;
    __shared__ float4 bs[PRE];
    for (int i = threadIdx.x; i < PRE; i += 256)
        bs[i] = *(const float4*)&topbox[((size_t)n*PRE + i)*4];
    __syncthreads();
    int i = chunk*16 + (threadIdx.x >> 4);   // row
    int w = threadIdx.x & 15;                // mask word
    if (i >= PRE) return;
    float4 bi = bs[i];
    float ai = (bi.z - bi.x + 1.f) * (bi.w - bi.y + 1.f);
    u64 m = 0;
    int jn = min(64, PRE - w*64);
    for (int jj = 0; jj < jn; ++jj) {
        int j = w*64 + jj;
        float4 bj = bs[j];
        float xx1 = fmaxf(bi.x, bj.x);
        float yy1 = fmaxf(bi.y, bj.y);
        float xx2 = fminf(bi.z, bj.z);
        float yy2 = fminf(bi.w, bj.w);
        float iw = fmaxf(xx2 - xx1 + 1.f, 0.f);
        float ih = fmaxf(yy2 - yy1 + 1.f, 0.f);
        float inter = iw * ih;
        float aj = (bj.z - bj.x + 1.f) * (bj.w - bj.y + 1.f);
        float iou = inter / (ai + aj - inter);
        if ((j > i) && (iou > 0.7f)) m |= (1ull << jj);
    }
    masks[((size_t)n*PRE + i)*16 + w] = m;
}

// ---- sequential NMS sweep (1 wave/batch, remv distributed over 16 lanes) + rois ----
__launch_bounds__(64)
__global__ void k_nms(const u64* __restrict__ masks, const float* __restrict__ topbox,
                      float* __restrict__ out)
{
    int n = blockIdx.x;
    int lane = threadIdx.x;
    int w = lane & 15;
    const u64* M = masks + (size_t)n*PRE*16;
    u64 remv = 0, keep = 0;
    u64 m0 = M[0*16+w], m1 = M[1*16+w], m2 = M[2*16+w], m3 = M[3*16+w];
    u64 m4 = M[4*16+w], m5 = M[5*16+w], m6 = M[6*16+w], m7 = M[7*16+w];
#define PROC(MR, II) { \
    int ii = (II); \
    u64 rw = __shfl(remv, ii >> 6, 64); \
    if (((rw >> (ii & 63)) & 1ull) == 0ull) { \
        remv |= MR; \
        if (w == (ii >> 6)) keep |= (1ull << (ii & 63)); \
    } }
    for (int b = 0; b < PRE; b += 8) {
        PROC(m0, b+0); m0 = (b+8  < PRE) ? M[(size_t)(b+8)*16 + w]  : 0ull;
        PROC(m1, b+1); m1 = (b+9  < PRE) ? M[(size_t)(b+9)*16 + w]  : 0ull;
        PROC(m2, b+2); m2 = (b+10 < PRE) ? M[(size_t)(b+10)*16 + w] : 0ull;
        PROC(m3, b+3); m3 = (b+11 < PRE) ? M[(size_t)(b+11)*16 + w] : 0ull;
        PROC(m4, b+4); m4 = (b+12 < PRE) ? M[(size_t)(b+12)*16 + w] : 0ull;
        PROC(m5, b+5); m5 = (b+13 < PRE) ? M[(size_t)(b+13)*16 + w] : 0ull;
        PROC(m6, b+6); m6 = (b+14 < PRE) ? M[(size_t)(b+14)*16 + w] : 0ull;
        PROC(m7, b+7); m7 = (b+15 < PRE) ? M[(size_t)(b+15)*16 + w] : 0ull;
    }
#undef PROC
    __shared__ int cnts[16];
    __shared__ int pfx[17];
    __shared__ u32 list[PRE];
    if (lane < 16) cnts[lane] = __popcll(keep);
    __syncthreads();
    if (lane == 0) {
        int s = 0;
        for (int t = 0; t < 16; ++t) { pfx[t] = s; s += cnts[t]; }
        pfx[16] = s;
    }
    __syncthreads();
    if (lane < 16) {
        int pos = pfx[lane];
        u64 kk = keep;
        for (int b = 0; b < 64; ++b)
            if ((kk >> b) & 1ull) list[pos++] = (u32)(lane*64 + b);
    }
    __syncthreads();
    int total = pfx[16];
    for (int k = lane; k < POST; k += 64) {
        float4 v = make_float4(0.f, 0.f, 0.f, 0.f);
        if (k < total) {
            u32 r = list[k];
            v = *(const float4*)&topbox[((size_t)n*PRE + r)*4];
        }
        *(float4*)&out[O_ROIS + ((size_t)n*POST + k)*4] = v;
    }
}

extern "C" void kernel_launch(void* const* d_in, const int* in_sizes, int n_in,
                              void* d_out, int out_size, void* d_ws, size_t ws_size,
                              hipStream_t stream)
{
    const float* x      = (const float*)d_in[0];
    const float* conv_w = (const float*)d_in[1];
    const float* conv_b = (const float*)d_in[2];
    const float* g1 = (const float*)d_in[3];
    const float* b1 = (const float*)d_in[4];
    const float* m1 = (const float*)d_in[5];
    const float* v1 = (const float*)d_in[6];
    const float* clsw = (const float*)d_in[7];
    const float* g2 = (const float*)d_in[8];
    const float* b2 = (const float*)d_in[9];
    const float* m2 = (const float*)d_in[10];
    const float* v2 = (const float*)d_in[11];
    const float* regw = (const float*)d_in[12];
    const float* g3 = (const float*)d_in[13];
    const float* b3 = (const float*)d_in[14];
    const float* m3 = (const float*)d_in[15];
    const float* v3 = (const float*)d_in[16];
    // d_in[17]/d_in[18] = img_h/img_w, fixed 1280 -> clip bound 1279.f hardcoded

    char* ws = (char*)d_ws;
    f16*   Wp     = (f16*)(ws + WS_WPREP);
    float* base   = (float*)(ws + WS_BASE);
    float* boxes  = (float*)(ws + WS_BOX);
    u32*   keys   = (u32*)(ws + WS_KEY);
    u32*   ghp    = (u32*)(ws + WS_GH);
    float* topbox = (float*)(ws + WS_TBOX);
    u64*   masks  = (u64*)(ws + WS_MASK);
    float* out = (float*)d_out;

    k_prepw<<<72, 256, 0, stream>>>(conv_w, Wp);
    k_conv3<<<800, 256, 0, stream>>>(x, Wp, conv_b, g1, b1, m1, v1, base);
    k_heads<<<100, 256, 0, stream>>>(base, clsw, regw, g2, b2, m2, v2, g3, b3, m3, v3,
                                     out, boxes, keys, ghp);
    k_select<<<4, 1024, 0, stream>>>(keys, ghp, boxes, topbox);
    k_iou<<<252, 256, 0, stream>>>(topbox, masks);
    k_nms<<<4, 64, 0, stream>>>(masks, topbox, out);
}

// Round 14
// 444.447 us; speedup vs baseline: 1.1421x; 1.0254x over previous
//
#include <hip/hip_runtime.h>
#include <stdint.h>

typedef unsigned int u32;
typedef unsigned long long u64;
typedef _Float16 f16;
typedef __attribute__((ext_vector_type(8))) _Float16 f16x8;
typedef __attribute__((ext_vector_type(4))) float f32x4;

#define NB 4
#define CIN 256
#define HW 80
#define PX (HW*HW)            // 6400
#define NA 9
#define NANCH (PX*NA)         // 57600
#define PRE 1000
#define POST 300
#define CANDN 4096

// d_out layout (floats): fg[4*57600], rpn_reg[4*57600*4], rois[4*300*4]
#define O_REG  (NB*NANCH)             // 230400
#define O_ROIS (O_REG + NB*NANCH*4)   // 1152000

// workspace byte offsets (all 16B aligned)
#define WS_WPREP 0ull          // 9*8*2*256*40 f16 = 2949120 B
#define WS_BASE  2949120ull    // 4*256*6400 f ([n][co][p]) = 26214400 B
#define WS_BOX   29163520ull   // 4*57600*4 f  = 3686400 B
#define WS_KEY   32849920ull   // 4*57600 u32  = 921600 B
#define WS_GH    33771520ull   // 4*50*2048 u32 (u16-packed 4096 bins) = 1638400 B
#define WS_TBOX  35868672ull   // 4*1000*4 f   = 64000 B
#define WS_MASK  35932672ull   // 4*1000*16 u64= 512000 B

// anchor widths/heights (base=32, scales 8/16/32, ratios .5/1/2 with np rounding)
__constant__ float c_aw[9] = {360.f,720.f,1440.f,256.f,512.f,1024.f,184.f,368.f,736.f};
__constant__ float c_ah[9] = {176.f,352.f,704.f,256.f,512.f,1024.f,368.f,736.f,1472.f};

// ---- weight prep: fp32 w[co][ci][t] -> fp16 (h, m=residual*4096) in staging layout
// Wp[(t*8+cib)*20480 + part*10240 + co*40 + ci_local], rows padded 32->40 (80B)
__global__ void k_prepw(const float* __restrict__ w, f16* __restrict__ Wp)
{
    int id = blockIdx.x*256 + threadIdx.x;
    if (id >= 9*8*256) return;
    int co = id & 255;
    int tc = id >> 8;            // t*8+cib
    int t = tc >> 3, cib = tc & 7;
    __align__(16) f16 hb[40];
    __align__(16) f16 mb[40];
    #pragma unroll
    for (int k = 32; k < 40; ++k) { hb[k] = (f16)0.f; mb[k] = (f16)0.f; }
    #pragma unroll
    for (int ci = 0; ci < 32; ++ci) {
        float wv = w[((size_t)co*256 + (cib*32 + ci))*9 + t];
        f16 h = (f16)wv;
        f16 m = (f16)((wv - (float)h) * 4096.f);
        hb[ci] = h; mb[ci] = m;
    }
    f16* oh = Wp + (size_t)tc*20480 + (size_t)co*40;
    f16* om = oh + 10240;
    #pragma unroll
    for (int k = 0; k < 5; ++k) {
        *(f16x8*)(oh + k*8) = *(const f16x8*)(hb + k*8);
        *(f16x8*)(om + k*8) = *(const f16x8*)(mb + k*8);
    }
}

// ---- conv3x3 (implicit GEMM, fp16-split MFMA) + bias + mish + bn1 -> base (NCHW fp32)
// r12-exact (best measured: 196 us). block: 256 thr = 4 waves (2co x 2px),
// tile 128co x 128px (16w x 8h), K-step 32ci x 9 taps, 2 barriers per tap.
__launch_bounds__(256, 2)
__global__ void k_conv3(const float* __restrict__ x, const f16* __restrict__ Wp,
                        const float* __restrict__ cbias,
                        const float* __restrict__ g1, const float* __restrict__ b1,
                        const float* __restrict__ m1, const float* __restrict__ v1,
                        float* __restrict__ base)
{
    __shared__ __align__(16) f16 ldsA[10240];  // [2 part][128 co][40 (32ci+pad)]
    __shared__ __align__(16) f16 ldsX[14400];  // [2 part][180 pos][40 (32ci+pad)]
    int tid = threadIdx.x;
    int lane = tid & 63, wid = tid >> 6;
    int q = lane >> 4, l16 = lane & 15;
    int wc = (wid >> 1) * 64, wr = (wid & 1) * 4;
    int bid = blockIdx.x;
    int cb = bid & 1, pxb = bid >> 1;
    int n = pxb / 50, rem = pxb % 50;
    int h0 = (rem / 5) * 8, w0 = (rem % 5) * 16;

    f32x4 acch[4][4], accl[4][4];
    #pragma unroll
    for (int i = 0; i < 4; ++i)
        #pragma unroll
        for (int j = 0; j < 4; ++j) {
            acch[i][j] = (f32x4){0.f,0.f,0.f,0.f};
            accl[i][j] = (f32x4){0.f,0.f,0.f,0.f};
        }

    const float* xn = x + (size_t)n*CIN*PX;

    for (int cb8 = 0; cb8 < 8; ++cb8) {
        int ci0 = cb8 * 32;
        for (int t = 0; t < 9; ++t) {
            __syncthreads();                    // all waves done reading prev tiles
            if (t == 0) {
                // stage X halo: 10 rows x 18 cols x 32 ci, fp32 -> (h, m*4096) fp16
                for (int task = tid; task < 320; task += 256) {
                    int r = task >> 5, ci = task & 31;
                    int hh = h0 - 1 + r;
                    bool rowok = (hh >= 0) && (hh < HW);
                    const float* src = xn + (size_t)(ci0 + ci)*PX + hh*HW + (w0 - 1);
                    f16* dh = ldsX + r*18*40 + ci;
                    f16* dm = dh + 7200;
                    #pragma unroll
                    for (int cc = 0; cc < 18; ++cc) {
                        int ww = w0 - 1 + cc;
                        float v = (rowok && ww >= 0 && ww < HW) ? src[cc] : 0.f;
                        f16 h = (f16)v;
                        f16 m = (f16)((v - (float)h) * 4096.f);
                        dh[cc*40] = h;
                        dm[cc*40] = m;
                    }
                }
            }
            // stage A: 10240 f16 = 1280 x 16B chunks, 5 per thread, coalesced
            {
                const f16* wsrc = Wp + (size_t)(t*8 + cb8)*20480;
                #pragma unroll
                for (int c = 0; c < 5; ++c) {
                    int idx = c*256 + tid;             // 0..1279
                    int part = idx / 640, off = idx - part*640;
                    *(f16x8*)(ldsA + (size_t)idx*8) =
                        *(const f16x8*)(wsrc + part*10240 + cb*5120 + off*8);
                }
            }
            __syncthreads();                    // staging visible

            int dh_ = t / 3, dw_ = t - dh_*3;
            f16x8 Ah[4], Am[4];
            #pragma unroll
            for (int i = 0; i < 4; ++i) {
                int e = (wc + i*16 + l16)*40 + q*8;
                Ah[i] = *(const f16x8*)(ldsA + e);
                Am[i] = *(const f16x8*)(ldsA + 5120 + e);
            }
            #pragma unroll
            for (int j = 0; j < 4; ++j) {
                int pos = (wr + j + dh_)*18 + l16 + dw_;
                int e = pos*40 + q*8;
                f16x8 Bh = *(const f16x8*)(ldsX + e);
                f16x8 Bm = *(const f16x8*)(ldsX + 7200 + e);
                #pragma unroll
                for (int i = 0; i < 4; ++i) {
                    acch[i][j] = __builtin_amdgcn_mfma_f32_16x16x32_f16(Ah[i], Bh, acch[i][j], 0, 0, 0);
                    accl[i][j] = __builtin_amdgcn_mfma_f32_16x16x32_f16(Ah[i], Bm, accl[i][j], 0, 0, 0);
                    accl[i][j] = __builtin_amdgcn_mfma_f32_16x16x32_f16(Am[i], Bh, accl[i][j], 0, 0, 0);
                }
            }
        }
    }
    // epilogue: combine splits, bias + mish + bn1, store NCHW fp32 ([n][co][p])
    #pragma unroll
    for (int i = 0; i < 4; ++i) {
        #pragma unroll
        for (int rg = 0; rg < 4; ++rg) {
            int co = cb*128 + wc + i*16 + q*4 + rg;
            float cbv = cbias[co];
            float inv = g1[co] / sqrtf(v1[co] + 1e-5f);
            float ad  = b1[co] - m1[co]*inv;
            #pragma unroll
            for (int j = 0; j < 4; ++j) {
                float tval = acch[i][j][rg] + accl[i][j][rg]*(1.f/4096.f) + cbv;
                float sp = fmaxf(tval, 0.f) + log1pf(expf(-fabsf(tval)));  // softplus
                float mi = tval * tanhf(sp);                               // mish
                int h = h0 + wr + j, w = w0 + l16;
                base[(size_t)(n*CIN + co)*PX + h*HW + w] = mi*inv + ad;
            }
        }
    }
}

// ---- FUSED: 1x1 heads + bn2/softmax + bn3 + decode + key + LDS hist ----
// 200 blocks x 128 thr; block = 128 px of one n (6400/128=50 blocks/n).
// reg/fg stay in registers -> decode is bit-exact vs separate kernels.
__launch_bounds__(128)
__global__ void k_heads(const float* __restrict__ base,
                        const float* __restrict__ clsw, const float* __restrict__ regw,
                        const float* __restrict__ g2, const float* __restrict__ b2,
                        const float* __restrict__ m2, const float* __restrict__ v2,
                        const float* __restrict__ g3, const float* __restrict__ b3,
                        const float* __restrict__ m3, const float* __restrict__ v3,
                        float* __restrict__ out, float* __restrict__ boxes,
                        u32* __restrict__ keys, u32* __restrict__ ghp)
{
    __shared__ float wt[256*56];   // [ci][co<54]  (co: 0..17 cls, 18..53 reg)
    __shared__ u32 hh[4096];
    int tid = threadIdx.x;
    for (int i = tid; i < 54*256; i += 128) {
        int co = i >> 8, ci = i & 255;
        float v = (co < 18) ? clsw[i] : regw[i - 18*256];
        wt[ci*56 + co] = v;
    }
    #pragma unroll
    for (int k = 0; k < 32; ++k) hh[tid + k*128] = 0;
    __syncthreads();
    int gp = blockIdx.x*128 + tid;           // 0..25599
    int n = gp / PX, p = gp % PX;
    float acc[54];
    #pragma unroll
    for (int i = 0; i < 54; ++i) acc[i] = 0.f;
    const float* bp = base + (size_t)n*CIN*PX + p;
    for (int ci = 0; ci < 256; ++ci) {
        float xv = bp[(size_t)ci*PX];        // coalesced: lanes read adjacent p
        const float* wr = &wt[ci*56];
        #pragma unroll
        for (int co = 0; co < 54; ++co) acc[co] = fmaf(wr[co], xv, acc[co]);
    }
    // fg (softmax) — keep in regs for decode
    float fgv[9];
    int fgb = n*NANCH + p*NA;
    #pragma unroll
    for (int a = 0; a < NA; ++a) {
        float i0 = g2[2*a]   / sqrtf(v2[2*a]   + 1e-5f);
        float i1 = g2[2*a+1] / sqrtf(v2[2*a+1] + 1e-5f);
        float s0 = acc[2*a]*i0   + (b2[2*a]   - m2[2*a]*i0);
        float s1 = acc[2*a+1]*i1 + (b2[2*a+1] - m2[2*a+1]*i1);
        float mx = fmaxf(s0, s1);
        float e0 = expf(s0 - mx), e1 = expf(s1 - mx);
        fgv[a] = e1 / (e0 + e1);
        out[fgb + a] = fgv[a];
    }
    // reg (bn3) — keep in regs for decode
    float regv[36];
    size_t rb = (size_t)O_REG + (size_t)n*NANCH*4 + (size_t)p*36;
    #pragma unroll
    for (int c = 0; c < 36; ++c) {
        float iv = g3[c] / sqrtf(v3[c] + 1e-5f);
        regv[c] = acc[18 + c]*iv + (b3[c] - m3[c]*iv);
        out[rb + c] = regv[c];
    }
    // decode + clip + min-size + sortable key + LDS hist
    int wx = p % HW, hy = p / HW;
    float acx = 16.f + 16.f*(float)wx;
    float acy = 16.f + 16.f*(float)hy;
    #pragma unroll
    for (int a = 0; a < NA; ++a) {
        float aw = c_aw[a], ah = c_ah[a];
        float pcx = regv[4*a+0]*aw + acx;
        float pcy = regv[4*a+1]*ah + acy;
        float pw = expf(regv[4*a+2])*aw;
        float ph = expf(regv[4*a+3])*ah;
        float x1 = fminf(fmaxf(pcx - 0.5f*pw, 0.f), 1279.f);
        float y1 = fminf(fmaxf(pcy - 0.5f*ph, 0.f), 1279.f);
        float x2 = fminf(fmaxf(pcx + 0.5f*pw, 0.f), 1279.f);
        float y2 = fminf(fmaxf(pcy + 0.5f*ph, 0.f), 1279.f);
        float wsz = x2 - x1 + 1.f, hsz = y2 - y1 + 1.f;
        float s = (wsz >= 16.f && hsz >= 16.f) ? fgv[a] : -1e9f;
        int i = p*NA + a;
        *(float4*)&boxes[((size_t)n*NANCH + i)*4] = make_float4(x1, y1, x2, y2);
        u32 u = __float_as_uint(s);
        u = (u & 0x80000000u) ? ~u : (u | 0x80000000u);
        keys[(size_t)n*NANCH + i] = u;
        atomicAdd(&hh[u >> 20], 1u);
    }
    __syncthreads();
    // pack block-local hist (u16 x2 per u32); slice = blk%50
    u32* gp2 = ghp + ((size_t)n*50 + (blockIdx.x % 50))*2048;
    #pragma unroll
    for (int k = 0; k < 16; ++k) {
        int j = tid + k*128;
        gp2[j] = (hh[2*j] & 0xFFFFu) | (hh[2*j+1] << 16);
    }
}

// ---- two-level (12+12 bit) radix-select + compact + adaptive bitonic -> top-1000 ----
__launch_bounds__(1024)
__global__ void k_select(const u32* __restrict__ keys, const u32* __restrict__ ghp,
                         const float* __restrict__ boxes, float* __restrict__ topbox)
{
    __shared__ u32 h1[4096];
    __shared__ u32 h2[4][4096];
    __shared__ u32 ss[1025];
    __shared__ int sB1, sA1, sB2, scnt;
    __shared__ u64 cand[CANDN];
    int n = blockIdx.x, tid = threadIdx.x, wid = tid >> 6;

    // pass 0: reduce 50 u16 slices -> h1
    const u32* gp = ghp + (size_t)n*50*2048;
    u32 c0=0,c1=0,c2=0,c3=0;
    for (int s = 0; s < 50; ++s) {
        const u32* w = gp + s*2048 + 2*tid;
        u32 a = w[0], b = w[1];
        c0 += a & 0xFFFFu; c1 += a >> 16; c2 += b & 0xFFFFu; c3 += b >> 16;
    }
    h1[4*tid+0]=c0; h1[4*tid+1]=c1; h1[4*tid+2]=c2; h1[4*tid+3]=c3;
    ss[tid] = c0+c1+c2+c3;
    if (tid == 0) scnt = 0;
    __syncthreads();
    for (int off = 1; off < 1024; off <<= 1) {   // suffix sums
        u32 v = (tid + off < 1024) ? ss[tid + off] : 0u;
        __syncthreads();
        ss[tid] += v;
        __syncthreads();
    }
    {
        u32 nxt = (tid == 1023) ? 0u : ss[tid + 1];
        if (ss[tid] >= PRE && nxt < PRE) {
            u32 c = nxt;
            for (int b = 4*tid+3; b >= 4*tid; --b) {
                c += h1[b];
                if (c >= PRE) { sB1 = b; sA1 = (int)(c - h1[b]); break; }
            }
        }
    }
    __syncthreads();
    int B1 = sB1, A1 = sA1;
    for (int k = tid; k < 4*4096; k += 1024) ((u32*)h2)[k] = 0;
    __syncthreads();

    // pass 1: emit strict-above candidates; histogram boundary bin's next 12 bits
    const u32* kp = keys + (size_t)n*NANCH;
    for (int i = tid; i < NANCH; i += 1024) {
        u32 k = kp[i];
        int top = (int)(k >> 20);
        if (top > B1) {
            int pos = atomicAdd(&scnt, 1);
            if (pos < CANDN) cand[pos] = ~(((u64)k << 32) | (u64)(0xFFFFFFFFu - (u32)i));
        } else if (top == B1) {
            atomicAdd(&h2[wid & 3][(k >> 8) & 0xFFFu], 1u);
        }
    }
    __syncthreads();
    {
        int b = 4*tid;
        u32 d0 = h2[0][b]+h2[1][b]+h2[2][b]+h2[3][b];
        u32 d1 = h2[0][b+1]+h2[1][b+1]+h2[2][b+1]+h2[3][b+1];
        u32 d2 = h2[0][b+2]+h2[1][b+2]+h2[2][b+2]+h2[3][b+2];
        u32 d3 = h2[0][b+3]+h2[1][b+3]+h2[2][b+3]+h2[3][b+3];
        ss[tid] = d0+d1+d2+d3;
    }
    __syncthreads();
    for (int off = 1; off < 1024; off <<= 1) {
        u32 v = (tid + off < 1024) ? ss[tid + off] : 0u;
        __syncthreads();
        ss[tid] += v;
        __syncthreads();
    }
    {
        u32 nxt = (tid == 1023) ? 0u : ss[tid + 1];
        if ((u32)A1 + ss[tid] >= PRE && (u32)A1 + nxt < PRE) {
            u32 c = (u32)A1 + nxt;
            for (int b = 4*tid+3; b >= 4*tid; --b) {
                u32 hv = h2[0][b]+h2[1][b]+h2[2][b]+h2[3][b];
                c += hv;
                if (c >= PRE) { sB2 = b; break; }
            }
        }
    }
    __syncthreads();
    int B2 = sB2;

    // pass 2: emit boundary-bin candidates with sub-key >= B2
    for (int i = tid; i < NANCH; i += 1024) {
        u32 k = kp[i];
        if ((int)(k >> 20) == B1 && (int)((k >> 8) & 0xFFFu) >= B2) {
            int pos = atomicAdd(&scnt, 1);
            if (pos < CANDN) cand[pos] = ~(((u64)k << 32) | (u64)(0xFFFFFFFFu - (u32)i));
        }
    }
    __syncthreads();
    int cnt = min(scnt, CANDN);
    int N = (cnt <= 2048) ? 2048 : CANDN;    // adaptive sort size (block-uniform)
    for (int i = cnt + tid; i < N; i += 1024) cand[i] = ~0ull;
    __syncthreads();
    for (int k = 2; k <= N; k <<= 1) {       // bitonic ascending = (score desc, idx asc)
        for (int j = k >> 1; j > 0; j >>= 1) {
            for (int t = tid; t < N/2; t += 1024) {
                int i1 = 2*t - (t & (j - 1));
                int i2 = i1 + j;
                u64 va = cand[i1], vb = cand[i2];
                bool up = ((i1 & k) == 0);
                if ((va > vb) == up) { cand[i1] = vb; cand[i2] = va; }
            }
            __syncthreads();
        }
    }
    for (int r = tid; r < PRE; r += 1024) {
        u64 c = ~cand[r];
        u32 idx = 0xFFFFFFFFu - (u32)(c & 0xFFFFFFFFull);
        *(float4*)&topbox[((size_t)n*PRE + r)*4] =
            *(const float4*)&boxes[((size_t)n*NANCH + idx)*4];
    }
}

// ---- IoU suppression bit-masks (252 blocks: 4 n x 63 chunks of 16 rows; 1 word/thr) ----
__launch_bounds__(256)
__global__ void k_iou(const float* __restrict__ topbox, u64* __restrict__ masks)
{
    int n = blockIdx.x / 63, chunk = blockIdx.x % 63;
    __shared__ float4 bs[PRE];
    for (int i = threadIdx.x; i < PRE; i += 256)
        bs[i] = *(const float4*)&topbox[((size_t)n*PRE + i)*4];
    __syncthreads();
    int i = chunk*16 + (threadIdx.x >> 4);   // row
    int w = threadIdx.x & 15;                // mask word
    if (i >= PRE) return;
    float4 bi = bs[i];
    float ai = (bi.z - bi.x + 1.f) * (bi.w - bi.y + 1.f);
    u64 m = 0;
    int jn = min(64, PRE - w*64);
    for (int jj = 0; jj < jn; ++jj) {
        int j = w*64 + jj;
        float4 bj = bs[j];
        float xx1 = fmaxf(bi.x, bj.x);
        float yy1 = fmaxf(bi.y, bj.y);
        float xx2 = fminf(bi.z, bj.z);
        float yy2 = fminf(bi.w, bj.w);
        float iw = fmaxf(xx2 - xx1 + 1.f, 0.f);
        float ih = fmaxf(yy2 - yy1 + 1.f, 0.f);
        float inter = iw * ih;
        float aj = (bj.z - bj.x + 1.f) * (bj.w - bj.y + 1.f);
        float iou = inter / (ai + aj - inter);
        if ((j > i) && (iou > 0.7f)) m |= (1ull << jj);
    }
    masks[((size_t)n*PRE + i)*16 + w] = m;
}

// ---- sequential NMS sweep (1 wave/batch, remv distributed over 16 lanes) + rois ----
__launch_bounds__(64)
__global__ void k_nms(const u64* __restrict__ masks, const float* __restrict__ topbox,
                      float* __restrict__ out)
{
    int n = blockIdx.x;
    int lane = threadIdx.x;
    int w = lane & 15;
    const u64* M = masks + (size_t)n*PRE*16;
    u64 remv = 0, keep = 0;
    u64 m0 = M[0*16+w], m1 = M[1*16+w], m2 = M[2*16+w], m3 = M[3*16+w];
    u64 m4 = M[4*16+w], m5 = M[5*16+w], m6 = M[6*16+w], m7 = M[7*16+w];
#define PROC(MR, II) { \
    int ii = (II); \
    u64 rw = __shfl(remv, ii >> 6, 64); \
    if (((rw >> (ii & 63)) & 1ull) == 0ull) { \
        remv |= MR; \
        if (w == (ii >> 6)) keep |= (1ull << (ii & 63)); \
    } }
    for (int b = 0; b < PRE; b += 8) {
        PROC(m0, b+0); m0 = (b+8  < PRE) ? M[(size_t)(b+8)*16 + w]  : 0ull;
        PROC(m1, b+1); m1 = (b+9  < PRE) ? M[(size_t)(b+9)*16 + w]  : 0ull;
        PROC(m2, b+2); m2 = (b+10 < PRE) ? M[(size_t)(b+10)*16 + w] : 0ull;
        PROC(m3, b+3); m3 = (b+11 < PRE) ? M[(size_t)(b+11)*16 + w] : 0ull;
        PROC(m4, b+4); m4 = (b+12 < PRE) ? M[(size_t)(b+12)*16 + w] : 0ull;
        PROC(m5, b+5); m5 = (b+13 < PRE) ? M[(size_t)(b+13)*16 + w] : 0ull;
        PROC(m6, b+6); m6 = (b+14 < PRE) ? M[(size_t)(b+14)*16 + w] : 0ull;
        PROC(m7, b+7); m7 = (b+15 < PRE) ? M[(size_t)(b+15)*16 + w] : 0ull;
    }
#undef PROC
    __shared__ int cnts[16];
    __shared__ int pfx[17];
    __shared__ u32 list[PRE];
    if (lane < 16) cnts[lane] = __popcll(keep);
    __syncthreads();
    if (lane == 0) {
        int s = 0;
        for (int t = 0; t < 16; ++t) { pfx[t] = s; s += cnts[t]; }
        pfx[16] = s;
    }
    __syncthreads();
    if (lane < 16) {
        int pos = pfx[lane];
        u64 kk = keep;
        for (int b = 0; b < 64; ++b)
            if ((kk >> b) & 1ull) list[pos++] = (u32)(lane*64 + b);
    }
    __syncthreads();
    int total = pfx[16];
    for (int k = lane; k < POST; k += 64) {
        float4 v = make_float4(0.f, 0.f, 0.f, 0.f);
        if (k < total) {
            u32 r = list[k];
            v = *(const float4*)&topbox[((size_t)n*PRE + r)*4];
        }
        *(float4*)&out[O_ROIS + ((size_t)n*POST + k)*4] = v;
    }
}

extern "C" void kernel_launch(void* const* d_in, const int* in_sizes, int n_in,
                              void* d_out, int out_size, void* d_ws, size_t ws_size,
                              hipStream_t stream)
{
    const float* x      = (const float*)d_in[0];
    const float* conv_w = (const float*)d_in[1];
    const float* conv_b = (const float*)d_in[2];
    const float* g1 = (const float*)d_in[3];
    const float* b1 = (const float*)d_in[4];
    const float* m1 = (const float*)d_in[5];
    const float* v1 = (const float*)d_in[6];
    const float* clsw = (const float*)d_in[7];
    const float* g2 = (const float*)d_in[8];
    const float* b2 = (const float*)d_in[9];
    const float* m2 = (const float*)d_in[10];
    const float* v2 = (const float*)d_in[11];
    const float* regw = (const float*)d_in[12];
    const float* g3 = (const float*)d_in[13];
    const float* b3 = (const float*)d_in[14];
    const float* m3 = (const float*)d_in[15];
    const float* v3 = (const float*)d_in[16];
    // d_in[17]/d_in[18] = img_h/img_w, fixed 1280 -> clip bound 1279.f hardcoded

    char* ws = (char*)d_ws;
    f16*   Wp     = (f16*)(ws + WS_WPREP);
    float* base   = (float*)(ws + WS_BASE);
    float* boxes  = (float*)(ws + WS_BOX);
    u32*   keys   = (u32*)(ws + WS_KEY);
    u32*   ghp    = (u32*)(ws + WS_GH);
    float* topbox = (float*)(ws + WS_TBOX);
    u64*   masks  = (u64*)(ws + WS_MASK);
    float* out = (float*)d_out;

    k_prepw<<<72, 256, 0, stream>>>(conv_w, Wp);
    k_conv3<<<400, 256, 0, stream>>>(x, Wp, conv_b, g1, b1, m1, v1, base);
    k_heads<<<200, 128, 0, stream>>>(base, clsw, regw, g2, b2, m2, v2, g3, b3, m3, v3,
                                     out, boxes, keys, ghp);
    k_select<<<4, 1024, 0, stream>>>(keys, ghp, boxes, topbox);
    k_iou<<<252, 256, 0, stream>>>(topbox, masks);
    k_nms<<<4, 64, 0, stream>>>(masks, topbox, out);
}

// Round 15
// 424.785 us; speedup vs baseline: 1.1950x; 1.0463x over previous
//
#include <hip/hip_runtime.h>
#include <stdint.h>

typedef unsigned int u32;
typedef unsigned long long u64;
typedef _Float16 f16;
typedef __attribute__((ext_vector_type(8))) _Float16 f16x8;
typedef __attribute__((ext_vector_type(4))) float f32x4;

#define NB 4
#define CIN 256
#define HW 80
#define PX (HW*HW)            // 6400
#define NA 9
#define NANCH (PX*NA)         // 57600
#define PRE 1000
#define POST 300
#define CANDN 4096

// d_out layout (floats): fg[4*57600], rpn_reg[4*57600*4], rois[4*300*4]
#define O_REG  (NB*NANCH)             // 230400
#define O_ROIS (O_REG + NB*NANCH*4)   // 1152000

// workspace byte offsets (all 16B aligned)
#define WS_WPREP 0ull          // 9*8*2*256*40 f16 = 2949120 B
#define WS_BASE  2949120ull    // 4*256*6400 f ([n][co][p]) = 26214400 B
#define WS_BOX   29163520ull   // 4*57600*4 f  = 3686400 B
#define WS_KEY   32849920ull   // 4*57600 u32  = 921600 B
#define WS_GH    33771520ull   // 4*25*2048 u32 (u16-packed 4096 bins) = 819200 B
#define WS_TBOX  35868672ull   // 4*1000*4 f   = 64000 B
#define WS_MASK  35932672ull   // 4*1000*16 u64= 512000 B

// anchor widths/heights (base=32, scales 8/16/32, ratios .5/1/2 with np rounding)
__constant__ float c_aw[9] = {360.f,720.f,1440.f,256.f,512.f,1024.f,184.f,368.f,736.f};
__constant__ float c_ah[9] = {176.f,352.f,704.f,256.f,512.f,1024.f,368.f,736.f,1472.f};

// ---- weight prep: fp32 w[co][ci][t] -> fp16 (h, m=residual*4096) in staging layout
// Wp[(t*8+cib)*20480 + part*10240 + co*40 + ci_local], rows padded 32->40 (80B)
__global__ void k_prepw(const float* __restrict__ w, f16* __restrict__ Wp)
{
    int id = blockIdx.x*256 + threadIdx.x;
    if (id >= 9*8*256) return;
    int co = id & 255;
    int tc = id >> 8;            // t*8+cib
    int t = tc >> 3, cib = tc & 7;
    __align__(16) f16 hb[40];
    __align__(16) f16 mb[40];
    #pragma unroll
    for (int k = 32; k < 40; ++k) { hb[k] = (f16)0.f; mb[k] = (f16)0.f; }
    #pragma unroll
    for (int ci = 0; ci < 32; ++ci) {
        float wv = w[((size_t)co*256 + (cib*32 + ci))*9 + t];
        f16 h = (f16)wv;
        f16 m = (f16)((wv - (float)h) * 4096.f);
        hb[ci] = h; mb[ci] = m;
    }
    f16* oh = Wp + (size_t)tc*20480 + (size_t)co*40;
    f16* om = oh + 10240;
    #pragma unroll
    for (int k = 0; k < 5; ++k) {
        *(f16x8*)(oh + k*8) = *(const f16x8*)(hb + k*8);
        *(f16x8*)(om + k*8) = *(const f16x8*)(mb + k*8);
    }
}

// ---- conv3x3 (implicit GEMM, fp16-split MFMA) + bias + mish + bn1 -> base (NCHW fp32)
// r12-exact (best measured: 196 us). block: 256 thr = 4 waves (2co x 2px),
// tile 128co x 128px (16w x 8h), K-step 32ci x 9 taps, 2 barriers per tap.
__launch_bounds__(256, 2)
__global__ void k_conv3(const float* __restrict__ x, const f16* __restrict__ Wp,
                        const float* __restrict__ cbias,
                        const float* __restrict__ g1, const float* __restrict__ b1,
                        const float* __restrict__ m1, const float* __restrict__ v1,
                        float* __restrict__ base)
{
    __shared__ __align__(16) f16 ldsA[10240];  // [2 part][128 co][40 (32ci+pad)]
    __shared__ __align__(16) f16 ldsX[14400];  // [2 part][180 pos][40 (32ci+pad)]
    int tid = threadIdx.x;
    int lane = tid & 63, wid = tid >> 6;
    int q = lane >> 4, l16 = lane & 15;
    int wc = (wid >> 1) * 64, wr = (wid & 1) * 4;
    int bid = blockIdx.x;
    int cb = bid & 1, pxb = bid >> 1;
    int n = pxb / 50, rem = pxb % 50;
    int h0 = (rem / 5) * 8, w0 = (rem % 5) * 16;

    f32x4 acch[4][4], accl[4][4];
    #pragma unroll
    for (int i = 0; i < 4; ++i)
        #pragma unroll
        for (int j = 0; j < 4; ++j) {
            acch[i][j] = (f32x4){0.f,0.f,0.f,0.f};
            accl[i][j] = (f32x4){0.f,0.f,0.f,0.f};
        }

    const float* xn = x + (size_t)n*CIN*PX;

    for (int cb8 = 0; cb8 < 8; ++cb8) {
        int ci0 = cb8 * 32;
        for (int t = 0; t < 9; ++t) {
            __syncthreads();                    // all waves done reading prev tiles
            if (t == 0) {
                // stage X halo: 10 rows x 18 cols x 32 ci, fp32 -> (h, m*4096) fp16
                for (int task = tid; task < 320; task += 256) {
                    int r = task >> 5, ci = task & 31;
                    int hh = h0 - 1 + r;
                    bool rowok = (hh >= 0) && (hh < HW);
                    const float* src = xn + (size_t)(ci0 + ci)*PX + hh*HW + (w0 - 1);
                    f16* dh = ldsX + r*18*40 + ci;
                    f16* dm = dh + 7200;
                    #pragma unroll
                    for (int cc = 0; cc < 18; ++cc) {
                        int ww = w0 - 1 + cc;
                        float v = (rowok && ww >= 0 && ww < HW) ? src[cc] : 0.f;
                        f16 h = (f16)v;
                        f16 m = (f16)((v - (float)h) * 4096.f);
                        dh[cc*40] = h;
                        dm[cc*40] = m;
                    }
                }
            }
            // stage A: 10240 f16 = 1280 x 16B chunks, 5 per thread, coalesced
            {
                const f16* wsrc = Wp + (size_t)(t*8 + cb8)*20480;
                #pragma unroll
                for (int c = 0; c < 5; ++c) {
                    int idx = c*256 + tid;             // 0..1279
                    int part = idx / 640, off = idx - part*640;
                    *(f16x8*)(ldsA + (size_t)idx*8) =
                        *(const f16x8*)(wsrc + part*10240 + cb*5120 + off*8);
                }
            }
            __syncthreads();                    // staging visible

            int dh_ = t / 3, dw_ = t - dh_*3;
            f16x8 Ah[4], Am[4];
            #pragma unroll
            for (int i = 0; i < 4; ++i) {
                int e = (wc + i*16 + l16)*40 + q*8;
                Ah[i] = *(const f16x8*)(ldsA + e);
                Am[i] = *(const f16x8*)(ldsA + 5120 + e);
            }
            #pragma unroll
            for (int j = 0; j < 4; ++j) {
                int pos = (wr + j + dh_)*18 + l16 + dw_;
                int e = pos*40 + q*8;
                f16x8 Bh = *(const f16x8*)(ldsX + e);
                f16x8 Bm = *(const f16x8*)(ldsX + 7200 + e);
                #pragma unroll
                for (int i = 0; i < 4; ++i) {
                    acch[i][j] = __builtin_amdgcn_mfma_f32_16x16x32_f16(Ah[i], Bh, acch[i][j], 0, 0, 0);
                    accl[i][j] = __builtin_amdgcn_mfma_f32_16x16x32_f16(Ah[i], Bm, accl[i][j], 0, 0, 0);
                    accl[i][j] = __builtin_amdgcn_mfma_f32_16x16x32_f16(Am[i], Bh, accl[i][j], 0, 0, 0);
                }
            }
        }
    }
    // epilogue: combine splits, bias + mish + bn1, store NCHW fp32 ([n][co][p])
    #pragma unroll
    for (int i = 0; i < 4; ++i) {
        #pragma unroll
        for (int rg = 0; rg < 4; ++rg) {
            int co = cb*128 + wc + i*16 + q*4 + rg;
            float cbv = cbias[co];
            float inv = g1[co] / sqrtf(v1[co] + 1e-5f);
            float ad  = b1[co] - m1[co]*inv;
            #pragma unroll
            for (int j = 0; j < 4; ++j) {
                float tval = acch[i][j][rg] + accl[i][j][rg]*(1.f/4096.f) + cbv;
                float sp = fmaxf(tval, 0.f) + log1pf(expf(-fabsf(tval)));  // softplus
                float mi = tval * tanhf(sp);                               // mish
                int h = h0 + wr + j, w = w0 + l16;
                base[(size_t)(n*CIN + co)*PX + h*HW + w] = mi*inv + ad;
            }
        }
    }
}

// ---- FUSED: 1x1 heads + bn2/softmax + bn3 + decode + key + LDS hist ----
// r13-measured grid: 100 blocks x 256 thr (25 slices/n). reg/fg stay in
// registers -> decode bit-exact vs separate kernels.
__launch_bounds__(256)
__global__ void k_heads(const float* __restrict__ base,
                        const float* __restrict__ clsw, const float* __restrict__ regw,
                        const float* __restrict__ g2, const float* __restrict__ b2,
                        const float* __restrict__ m2, const float* __restrict__ v2,
                        const float* __restrict__ g3, const float* __restrict__ b3,
                        const float* __restrict__ m3, const float* __restrict__ v3,
                        float* __restrict__ out, float* __restrict__ boxes,
                        u32* __restrict__ keys, u32* __restrict__ ghp)
{
    __shared__ float wt[256*56];   // [ci][co<54]  (co: 0..17 cls, 18..53 reg)
    __shared__ u32 hh[4096];
    int tid = threadIdx.x;
    for (int i = tid; i < 54*256; i += 256) {
        int co = i >> 8, ci = i & 255;
        float v = (co < 18) ? clsw[i] : regw[i - 18*256];
        wt[ci*56 + co] = v;
    }
    #pragma unroll
    for (int k = 0; k < 16; ++k) hh[tid + k*256] = 0;
    __syncthreads();
    int gp = blockIdx.x*256 + tid;           // 0..25599
    int n = gp / PX, p = gp % PX;
    float acc[54];
    #pragma unroll
    for (int i = 0; i < 54; ++i) acc[i] = 0.f;
    const float* bp = base + (size_t)n*CIN*PX + p;
    for (int ci = 0; ci < 256; ++ci) {
        float xv = bp[(size_t)ci*PX];        // coalesced: lanes read adjacent p
        const float* wr = &wt[ci*56];
        #pragma unroll
        for (int co = 0; co < 54; ++co) acc[co] = fmaf(wr[co], xv, acc[co]);
    }
    // fg (softmax) — keep in regs for decode
    float fgv[9];
    int fgb = n*NANCH + p*NA;
    #pragma unroll
    for (int a = 0; a < NA; ++a) {
        float i0 = g2[2*a]   / sqrtf(v2[2*a]   + 1e-5f);
        float i1 = g2[2*a+1] / sqrtf(v2[2*a+1] + 1e-5f);
        float s0 = acc[2*a]*i0   + (b2[2*a]   - m2[2*a]*i0);
        float s1 = acc[2*a+1]*i1 + (b2[2*a+1] - m2[2*a+1]*i1);
        float mx = fmaxf(s0, s1);
        float e0 = expf(s0 - mx), e1 = expf(s1 - mx);
        fgv[a] = e1 / (e0 + e1);
        out[fgb + a] = fgv[a];
    }
    // reg (bn3) — keep in regs for decode
    float regv[36];
    size_t rb = (size_t)O_REG + (size_t)n*NANCH*4 + (size_t)p*36;
    #pragma unroll
    for (int c = 0; c < 36; ++c) {
        float iv = g3[c] / sqrtf(v3[c] + 1e-5f);
        regv[c] = acc[18 + c]*iv + (b3[c] - m3[c]*iv);
        out[rb + c] = regv[c];
    }
    // decode + clip + min-size + sortable key + LDS hist
    int wx = p % HW, hy = p / HW;
    float acx = 16.f + 16.f*(float)wx;
    float acy = 16.f + 16.f*(float)hy;
    #pragma unroll
    for (int a = 0; a < NA; ++a) {
        float aw = c_aw[a], ah = c_ah[a];
        float pcx = regv[4*a+0]*aw + acx;
        float pcy = regv[4*a+1]*ah + acy;
        float pw = expf(regv[4*a+2])*aw;
        float ph = expf(regv[4*a+3])*ah;
        float x1 = fminf(fmaxf(pcx - 0.5f*pw, 0.f), 1279.f);
        float y1 = fminf(fmaxf(pcy - 0.5f*ph, 0.f), 1279.f);
        float x2 = fminf(fmaxf(pcx + 0.5f*pw, 0.f), 1279.f);
        float y2 = fminf(fmaxf(pcy + 0.5f*ph, 0.f), 1279.f);
        float wsz = x2 - x1 + 1.f, hsz = y2 - y1 + 1.f;
        float s = (wsz >= 16.f && hsz >= 16.f) ? fgv[a] : -1e9f;
        int i = p*NA + a;
        *(float4*)&boxes[((size_t)n*NANCH + i)*4] = make_float4(x1, y1, x2, y2);
        u32 u = __float_as_uint(s);
        u = (u & 0x80000000u) ? ~u : (u | 0x80000000u);
        keys[(size_t)n*NANCH + i] = u;
        atomicAdd(&hh[u >> 20], 1u);
    }
    __syncthreads();
    // pack block-local hist (u16 x2 per u32); slice = blk%25
    u32* gp2 = ghp + ((size_t)n*25 + (blockIdx.x % 25))*2048;
    #pragma unroll
    for (int k = 0; k < 8; ++k) {
        int j = tid + k*256;
        gp2[j] = (hh[2*j] & 0xFFFFu) | (hh[2*j+1] << 16);
    }
}

// ---- two-level (12+12 bit) radix-select + compact + RANK-SCATTER -> top-1000 ----
__launch_bounds__(1024)
__global__ void k_select(const u32* __restrict__ keys, const u32* __restrict__ ghp,
                         const float* __restrict__ boxes, float* __restrict__ topbox)
{
    __shared__ u32 h1[4096];
    __shared__ u32 h2[4][4096];
    __shared__ u32 ss[1025];
    __shared__ int sB1, sA1, sB2, scnt;
    __shared__ u64 cand[CANDN];
    int n = blockIdx.x, tid = threadIdx.x, wid = tid >> 6;

    // pass 0: reduce 25 u16 slices -> h1
    const u32* gp = ghp + (size_t)n*25*2048;
    u32 c0=0,c1=0,c2=0,c3=0;
    for (int s = 0; s < 25; ++s) {
        const u32* w = gp + s*2048 + 2*tid;
        u32 a = w[0], b = w[1];
        c0 += a & 0xFFFFu; c1 += a >> 16; c2 += b & 0xFFFFu; c3 += b >> 16;
    }
    h1[4*tid+0]=c0; h1[4*tid+1]=c1; h1[4*tid+2]=c2; h1[4*tid+3]=c3;
    ss[tid] = c0+c1+c2+c3;
    if (tid == 0) scnt = 0;
    __syncthreads();
    for (int off = 1; off < 1024; off <<= 1) {   // suffix sums
        u32 v = (tid + off < 1024) ? ss[tid + off] : 0u;
        __syncthreads();
        ss[tid] += v;
        __syncthreads();
    }
    {
        u32 nxt = (tid == 1023) ? 0u : ss[tid + 1];
        if (ss[tid] >= PRE && nxt < PRE) {
            u32 c = nxt;
            for (int b = 4*tid+3; b >= 4*tid; --b) {
                c += h1[b];
                if (c >= PRE) { sB1 = b; sA1 = (int)(c - h1[b]); break; }
            }
        }
    }
    __syncthreads();
    int B1 = sB1, A1 = sA1;
    for (int k = tid; k < 4*4096; k += 1024) ((u32*)h2)[k] = 0;
    __syncthreads();

    // pass 1: emit strict-above candidates; histogram boundary bin's next 12 bits
    const u32* kp = keys + (size_t)n*NANCH;
    for (int i = tid; i < NANCH; i += 1024) {
        u32 k = kp[i];
        int top = (int)(k >> 20);
        if (top > B1) {
            int pos = atomicAdd(&scnt, 1);
            if (pos < CANDN) cand[pos] = ~(((u64)k << 32) | (u64)(0xFFFFFFFFu - (u32)i));
        } else if (top == B1) {
            atomicAdd(&h2[wid & 3][(k >> 8) & 0xFFFu], 1u);
        }
    }
    __syncthreads();
    {
        int b = 4*tid;
        u32 d0 = h2[0][b]+h2[1][b]+h2[2][b]+h2[3][b];
        u32 d1 = h2[0][b+1]+h2[1][b+1]+h2[2][b+1]+h2[3][b+1];
        u32 d2 = h2[0][b+2]+h2[1][b+2]+h2[2][b+2]+h2[3][b+2];
        u32 d3 = h2[0][b+3]+h2[1][b+3]+h2[2][b+3]+h2[3][b+3];
        ss[tid] = d0+d1+d2+d3;
    }
    __syncthreads();
    for (int off = 1; off < 1024; off <<= 1) {
        u32 v = (tid + off < 1024) ? ss[tid + off] : 0u;
        __syncthreads();
        ss[tid] += v;
        __syncthreads();
    }
    {
        u32 nxt = (tid == 1023) ? 0u : ss[tid + 1];
        if ((u32)A1 + ss[tid] >= PRE && (u32)A1 + nxt < PRE) {
            u32 c = (u32)A1 + nxt;
            for (int b = 4*tid+3; b >= 4*tid; --b) {
                u32 hv = h2[0][b]+h2[1][b]+h2[2][b]+h2[3][b];
                c += hv;
                if (c >= PRE) { sB2 = b; break; }
            }
        }
    }
    __syncthreads();
    int B2 = sB2;

    // pass 2: emit boundary-bin candidates with sub-key >= B2
    for (int i = tid; i < NANCH; i += 1024) {
        u32 k = kp[i];
        if ((int)(k >> 20) == B1 && (int)((k >> 8) & 0xFFFu) >= B2) {
            int pos = atomicAdd(&scnt, 1);
            if (pos < CANDN) cand[pos] = ~(((u64)k << 32) | (u64)(0xFFFFFFFFu - (u32)i));
        }
    }
    __syncthreads();
    int cnt = min(scnt, CANDN);                 // cnt >= PRE by construction
    // rank-scatter: keys unique (idx embedded) -> rank = #{cand smaller}.
    // Ascending cand == (score desc, idx asc). Barrier-free, broadcast reads.
    for (int r = tid; r < cnt; r += 1024) {
        u64 mine = cand[r];
        int rank = 0;
        for (int i = 0; i < cnt; ++i)
            rank += (cand[i] < mine) ? 1 : 0;
        if (rank < PRE) {
            u64 c = ~mine;
            u32 idx = 0xFFFFFFFFu - (u32)(c & 0xFFFFFFFFull);
            *(float4*)&topbox[((size_t)n*PRE + rank)*4] =
                *(const float4*)&boxes[((size_t)n*NANCH + idx)*4];
        }
    }
}

// ---- IoU suppression bit-masks (252 blocks: 4 n x 63 chunks of 16 rows; 1 word/thr) ----
__launch_bounds__(256)
__global__ void k_iou(const float* __restrict__ topbox, u64* __restrict__ masks)
{
    int n = blockIdx.x / 63, chunk = blockIdx.x % 63;
    __shared__ float4 bs[PRE];
    for (int i = threadIdx.x; i < PRE; i += 256)
        bs[i] = *(const float4*)&topbox[((size_t)n*PRE + i)*4];
    __syncthreads();
    int i = chunk*16 + (threadIdx.x >> 4);   // row
    int w = threadIdx.x & 15;                // mask word
    if (i >= PRE) return;
    float4 bi = bs[i];
    float ai = (bi.z - bi.x + 1.f) * (bi.w - bi.y + 1.f);
    u64 m = 0;
    int jn = min(64, PRE - w*64);
    for (int jj = 0; jj < jn; ++jj) {
        int j = w*64 + jj;
        float4 bj = bs[j];
        float xx1 = fmaxf(bi.x, bj.x);
        float yy1 = fmaxf(bi.y, bj.y);
        float xx2 = fminf(bi.z, bj.z);
        float yy2 = fminf(bi.w, bj.w);
        float iw = fmaxf(xx2 - xx1 + 1.f, 0.f);
        float ih = fmaxf(yy2 - yy1 + 1.f, 0.f);
        float inter = iw * ih;
        float aj = (bj.z - bj.x + 1.f) * (bj.w - bj.y + 1.f);
        float iou = inter / (ai + aj - inter);
        if ((j > i) && (iou > 0.7f)) m |= (1ull << jj);
    }
    masks[((size_t)n*PRE + i)*16 + w] = m;
}

// ---- sequential NMS sweep (1 wave/batch; 24-deep triple-buffered prefetch) ----
__launch_bounds__(64)
__global__ void k_nms(const u64* __restrict__ masks, const float* __restrict__ topbox,
                      float* __restrict__ out)
{
    int n = blockIdx.x;
    int lane = threadIdx.x;
    int w = lane & 15;
    const u64* M = masks + (size_t)n*PRE*16;
    u64 remv = 0, keep = 0;
    u64 A[8], B_[8], C[8];
#define LOAD8(DST, BASE) { _Pragma("unroll") for (int z = 0; z < 8; ++z) { \
    int rr = (BASE) + z; DST[z] = (rr < PRE) ? M[(size_t)rr*16 + w] : 0ull; } }
#define PROC8(R, BASE) { _Pragma("unroll") for (int z = 0; z < 8; ++z) { \
    int ii = (BASE) + z; \
    if (ii < PRE) { \
        u64 rw = __shfl(remv, ii >> 6, 64); \
        if (((rw >> (ii & 63)) & 1ull) == 0ull) { \
            remv |= R[z]; \
            if (w == (ii >> 6)) keep |= (1ull << (ii & 63)); \
        } } } }
    LOAD8(A, 0)
    LOAD8(B_, 8)
    LOAD8(C, 16)
    for (int b = 0; b < PRE; b += 24) {          // loads run 3 batches (~500+ cy) ahead
        PROC8(A, b)       LOAD8(A, b + 24)
        PROC8(B_, b + 8)  LOAD8(B_, b + 32)
        PROC8(C, b + 16)  LOAD8(C, b + 40)
    }
#undef PROC8
#undef LOAD8
    __shared__ int cnts[16];
    __shared__ int pfx[17];
    __shared__ u32 list[PRE];
    if (lane < 16) cnts[lane] = __popcll(keep);
    __syncthreads();
    if (lane == 0) {
        int s = 0;
        for (int t = 0; t < 16; ++t) { pfx[t] = s; s += cnts[t]; }
        pfx[16] = s;
    }
    __syncthreads();
    if (lane < 16) {
        int pos = pfx[lane];
        u64 kk = keep;
        for (int b = 0; b < 64; ++b)
            if ((kk >> b) & 1ull) list[pos++] = (u32)(lane*64 + b);
    }
    __syncthreads();
    int total = pfx[16];
    for (int k = lane; k < POST; k += 64) {
        float4 v = make_float4(0.f, 0.f, 0.f, 0.f);
        if (k < total) {
            u32 r = list[k];
            v = *(const float4*)&topbox[((size_t)n*PRE + r)*4];
        }
        *(float4*)&out[O_ROIS + ((size_t)n*POST + k)*4] = v;
    }
}

extern "C" void kernel_launch(void* const* d_in, const int* in_sizes, int n_in,
                              void* d_out, int out_size, void* d_ws, size_t ws_size,
                              hipStream_t stream)
{
    const float* x      = (const float*)d_in[0];
    const float* conv_w = (const float*)d_in[1];
    const float* conv_b = (const float*)d_in[2];
    const float* g1 = (const float*)d_in[3];
    const float* b1 = (const float*)d_in[4];
    const float* m1 = (const float*)d_in[5];
    const float* v1 = (const float*)d_in[6];
    const float* clsw = (const float*)d_in[7];
    const float* g2 = (const float*)d_in[8];
    const float* b2 = (const float*)d_in[9];
    const float* m2 = (const float*)d_in[10];
    const float* v2 = (const float*)d_in[11];
    const float* regw = (const float*)d_in[12];
    const float* g3 = (const float*)d_in[13];
    const float* b3 = (const float*)d_in[14];
    const float* m3 = (const float*)d_in[15];
    const float* v3 = (const float*)d_in[16];
    // d_in[17]/d_in[18] = img_h/img_w, fixed 1280 -> clip bound 1279.f hardcoded

    char* ws = (char*)d_ws;
    f16*   Wp     = (f16*)(ws + WS_WPREP);
    float* base   = (float*)(ws + WS_BASE);
    float* boxes  = (float*)(ws + WS_BOX);
    u32*   keys   = (u32*)(ws + WS_KEY);
    u32*   ghp    = (u32*)(ws + WS_GH);
    float* topbox = (float*)(ws + WS_TBOX);
    u64*   masks  = (u64*)(ws + WS_MASK);
    float* out = (float*)d_out;

    k_prepw<<<72, 256, 0, stream>>>(conv_w, Wp);
    k_conv3<<<400, 256, 0, stream>>>(x, Wp, conv_b, g1, b1, m1, v1, base);
    k_heads<<<100, 256, 0, stream>>>(base, clsw, regw, g2, b2, m2, v2, g3, b3, m3, v3,
                                     out, boxes, keys, ghp);
    k_select<<<4, 1024, 0, stream>>>(keys, ghp, boxes, topbox);
    k_iou<<<252, 256, 0, stream>>>(topbox, masks);
    k_nms<<<4, 64, 0, stream>>>(masks, topbox, out);
}